// Round 2
// baseline (714.645 us; speedup 1.0000x reference)
//
#include <hip/hip_runtime.h>
#include <stdint.h>

#define MODEL 1024
#define INNER 4096
#define NHEADS 16
#define HDIM 64
#define BATCH 4
#define SEQ 2048
#define MROWS (BATCH*SEQ)

typedef __bf16 bf16x8 __attribute__((ext_vector_type(8)));
typedef float f32x4 __attribute__((ext_vector_type(4)));
typedef unsigned short ushort8 __attribute__((ext_vector_type(8)));
typedef unsigned short ushort4v __attribute__((ext_vector_type(4)));

__device__ __forceinline__ unsigned short f2bf(float f) {
  unsigned u = __builtin_bit_cast(unsigned, f);
  u += 0x7FFFu + ((u >> 16) & 1u);
  return (unsigned short)(u >> 16);
}

#define AS1 __attribute__((address_space(1)))
#define AS3 __attribute__((address_space(3)))
__device__ __forceinline__ void gload_lds16(const void* g, void* l) {
  __builtin_amdgcn_global_load_lds((const AS1 void*)g, (AS3 void*)l, 16, 0, 0);
}

// ---------------- fp32 -> bf16 convert (vectorized) ----------------
__global__ __launch_bounds__(256) void k_cvt(const float* __restrict__ in,
                                             unsigned short* __restrict__ out, int n4) {
  int i = blockIdx.x * 256 + threadIdx.x;
  if (i < n4) {
    float4 v = ((const float4*)in)[i];
    ushort4v o = { f2bf(v.x), f2bf(v.y), f2bf(v.z), f2bf(v.w) };
    ((ushort4v*)out)[i] = o;
  }
}

// ---------------- W [K][N] fp32 -> Wt [N][K] bf16 ----------------
__global__ __launch_bounds__(256) void k_transpose(const float* __restrict__ W,
                                                   unsigned short* __restrict__ Wt,
                                                   int K, int N) {
  __shared__ float tile[32][33];
  const int n0 = blockIdx.x * 32, k0 = blockIdx.y * 32;
  const int c = threadIdx.x & 31, r4 = threadIdx.x >> 5; // r4 in 0..7
#pragma unroll
  for (int i = 0; i < 4; i++) {
    int r = r4 + i * 8;
    tile[r][c] = W[(size_t)(k0 + r) * N + n0 + c];
  }
  __syncthreads();
#pragma unroll
  for (int i = 0; i < 4; i++) {
    int r = r4 + i * 8;
    Wt[(size_t)(n0 + r) * K + k0 + c] = f2bf(tile[c][r]);
  }
}

// ---------------- GEMM: C[M][N] = A[M][K] * Bt[N][K]^T + bias ----------------
// OUTMODE: 0 = fp32, 1 = bf16, 2 = bf16 + relu.  BROW: bias indexed by row.
// 2-phase pipelined: stage(t+1) issued before compute(t), one barrier/K-step.
template <int OUTMODE, bool BROW>
__global__ __launch_bounds__(256) void k_gemm(const unsigned short* __restrict__ A,
                                              const unsigned short* __restrict__ Bt,
                                              const float* __restrict__ bias,
                                              void* __restrict__ Cout,
                                              int M, int N, int K) {
  __shared__ unsigned short As[2][128 * 32];
  __shared__ unsigned short Bs[2][128 * 32];
  const int t = threadIdx.x;
  const int lane = t & 63;
  const int w = t >> 6;
  const int li = lane & 15, lg = lane >> 4;
  const int bm = blockIdx.y * 128, bn = blockIdx.x * 128;
  const int wm = (w >> 1) * 64, wn = (w & 1) * 64;
  const int sc = (t & 3) * 8;     // staging col (8 bf16 = 16B)
  const int sr = t >> 2;          // staging row 0..63
  f32x4 acc[4][4] = {};
  const unsigned short* Abase = A + (size_t)(bm + sr) * K + sc;
  const unsigned short* Bbase = Bt + (size_t)(bn + sr) * K + sc;

  auto stage = [&](int buf, int k0) {
    gload_lds16(Abase + k0, &As[buf][w * 512]);
    gload_lds16(Abase + (size_t)64 * K + k0, &As[buf][2048 + w * 512]);
    gload_lds16(Bbase + k0, &Bs[buf][w * 512]);
    gload_lds16(Bbase + (size_t)64 * K + k0, &Bs[buf][2048 + w * 512]);
  };
  auto compute = [&](int buf) {
    bf16x8 a[4], b[4];
#pragma unroll
    for (int m = 0; m < 4; m++)
      a[m] = *(const bf16x8*)&As[buf][(wm + m * 16 + li) * 32 + lg * 8];
#pragma unroll
    for (int n = 0; n < 4; n++)
      b[n] = *(const bf16x8*)&Bs[buf][(wn + n * 16 + li) * 32 + lg * 8];
#pragma unroll
    for (int m = 0; m < 4; m++)
#pragma unroll
      for (int n = 0; n < 4; n++)
        acc[m][n] = __builtin_amdgcn_mfma_f32_16x16x32_bf16(a[m], b[n], acc[m][n], 0, 0, 0);
  };

  stage(0, 0);
  __syncthreads();
  int cur = 0;
  for (int k0 = 32; k0 < K; k0 += 32) {
    stage(cur ^ 1, k0);
    compute(cur);
    __syncthreads();
    cur ^= 1;
  }
  compute(cur);

#pragma unroll
  for (int m = 0; m < 4; m++) {
    const int row = bm + wm + m * 16 + lg * 4;
#pragma unroll
    for (int n = 0; n < 4; n++) {
      const int col = bn + wn + n * 16 + li;
      const float bvc = BROW ? 0.f : bias[col];
#pragma unroll
      for (int j = 0; j < 4; j++) {
        float v = acc[m][n][j] + (BROW ? bias[row + j] : bvc);
        if (OUTMODE == 2) v = fmaxf(v, 0.f);
        if (OUTMODE == 0)
          ((float*)Cout)[(size_t)(row + j) * N + col] = v;
        else
          ((unsigned short*)Cout)[(size_t)(row + j) * N + col] = f2bf(v);
      }
    }
  }
}

// ---------------- flash attention ----------------
// q,k: bf16 [B*S][MODEL] ; vt: bf16 [MODEL][B*S] (pre-transposed) ; ctx: bf16 [B*S][MODEL]
// All LDS tiles XOR-swizzled (both-sides: pre-swizzled global source for
// gload_lds tiles, swizzled write for Ps) so every ds_read_b128 hits the
// 8-phase wave64 floor.
__global__ __launch_bounds__(256) void k_attn(const unsigned short* __restrict__ q,
                                              const unsigned short* __restrict__ kptr,
                                              const unsigned short* __restrict__ vt,
                                              const int* __restrict__ mask,
                                              unsigned short* __restrict__ ctx) {
  __shared__ unsigned short Ks[128 * 64];     // [kv][d], rows 128B, swz (row&7)<<4
  __shared__ unsigned short Vs[64 * 128];     // [d][kv], rows 256B, swz (row&15)<<4
  __shared__ unsigned short Ps[4][32 * 128];  // per-wave [q][kv], rows 256B, swz (row&15)<<4
  const int t = threadIdx.x, lane = t & 63, w = t >> 6;
  const int li = lane & 15, lg = lane >> 4;
  const int bh = blockIdx.y, b = bh >> 4, h = bh & 15;
  const int q0 = blockIdx.x * 128;
  const size_t basebs = (size_t)b * SEQ;

  bf16x8 qf[2][2];
#pragma unroll
  for (int m = 0; m < 2; m++)
#pragma unroll
    for (int kk = 0; kk < 2; kk++) {
      int row = q0 + w * 32 + m * 16 + li;
      qf[m][kk] = *(const bf16x8*)&q[(basebs + row) * MODEL + h * 64 + kk * 32 + lg * 8];
    }

  f32x4 acc_o[2][4] = {};
  float mrow[2][4], lrow[2][4];
#pragma unroll
  for (int m = 0; m < 2; m++)
#pragma unroll
    for (int j = 0; j < 4; j++) { mrow[m][j] = -3e38f; lrow[m][j] = 0.f; }

  const int sr = t >> 3;                          // 0..31 (K staging row)
  const int swK = ((t & 7) ^ (sr & 7)) * 8;       // pre-swizzled K source col (ushort)
  const int swV = ((t & 15) ^ ((t >> 4) & 15)) * 8; // pre-swizzled V source col (ushort)
  const int psw = li << 3;                        // read-side swizzle term (ushort)

  for (int kt = 0; kt < SEQ; kt += 128) {
    // stage K tile [128][64] via gload_lds, source-col swizzled
#pragma unroll
    for (int i = 0; i < 4; i++) {
      const unsigned short* g = kptr + (basebs + kt + sr + 32 * i) * MODEL + h * 64 + swK;
      gload_lds16(g, &Ks[w * 512 + i * 2048]);
    }
    // stage Vt tile [64][128] via gload_lds, source-col swizzled
#pragma unroll
    for (int i = 0; i < 4; i++) {
      int d = i * 16 + (t >> 4);
      const unsigned short* g = vt + (size_t)(h * 64 + d) * MROWS + b * SEQ + kt + swV;
      gload_lds16(g, &Vs[i * 2048 + w * 512]);
    }
    __syncthreads();

    int mk[8];
#pragma unroll
    for (int n = 0; n < 8; n++) mk[n] = mask[b * SEQ + kt + n * 16 + li];

    // S = Q K^T
    f32x4 sacc[2][8] = {};
#pragma unroll
    for (int n = 0; n < 8; n++) {
      const int rr = (n * 16 + li) * 64;
      const int kw = (li & 7) << 3;
      bf16x8 kf0 = *(const bf16x8*)&Ks[rr + ((lg * 8) ^ kw)];
      bf16x8 kf1 = *(const bf16x8*)&Ks[rr + ((32 + lg * 8) ^ kw)];
#pragma unroll
      for (int m = 0; m < 2; m++) {
        sacc[m][n] = __builtin_amdgcn_mfma_f32_16x16x32_bf16(qf[m][0], kf0, sacc[m][n], 0, 0, 0);
        sacc[m][n] = __builtin_amdgcn_mfma_f32_16x16x32_bf16(qf[m][1], kf1, sacc[m][n], 0, 0, 0);
      }
    }

    // online softmax (row q = m*16+lg*4+j, cols across li)
#pragma unroll
    for (int m = 0; m < 2; m++) {
#pragma unroll
      for (int j = 0; j < 4; j++) {
        float rmax = -3e38f;
#pragma unroll
        for (int n = 0; n < 8; n++) {
          float sv = sacc[m][n][j] * 0.125f;
          sv = (mk[n] == 0) ? -1e10f : sv;
          sacc[m][n][j] = sv;
          rmax = fmaxf(rmax, sv);
        }
        rmax = fmaxf(rmax, __shfl_xor(rmax, 1));
        rmax = fmaxf(rmax, __shfl_xor(rmax, 2));
        rmax = fmaxf(rmax, __shfl_xor(rmax, 4));
        rmax = fmaxf(rmax, __shfl_xor(rmax, 8));
        float mnew = fmaxf(mrow[m][j], rmax);
        float alpha = __expf(mrow[m][j] - mnew);
        mrow[m][j] = mnew;
        float rsum = 0.f;
#pragma unroll
        for (int n = 0; n < 8; n++) {
          float p = __expf(sacc[m][n][j] - mnew);
          sacc[m][n][j] = p;
          rsum += p;
        }
        rsum += __shfl_xor(rsum, 1);
        rsum += __shfl_xor(rsum, 2);
        rsum += __shfl_xor(rsum, 4);
        rsum += __shfl_xor(rsum, 8);
        lrow[m][j] = lrow[m][j] * alpha + rsum;
#pragma unroll
        for (int nd = 0; nd < 4; nd++) acc_o[m][nd][j] *= alpha;
      }
    }

    // P -> LDS (per-wave buffer), swizzled write
#pragma unroll
    for (int m = 0; m < 2; m++)
#pragma unroll
      for (int n = 0; n < 8; n++)
#pragma unroll
        for (int j = 0; j < 4; j++) {
          const int r15 = lg * 4 + j;
          Ps[w][(m * 16 + r15) * 128 + ((n * 16 + li) ^ (r15 << 3))] = f2bf(sacc[m][n][j]);
        }
    asm volatile("s_waitcnt lgkmcnt(0)" ::: "memory");

    // O += P V   (both Ps and Vs read at the swizzled offsets)
#pragma unroll
    for (int kk = 0; kk < 4; kk++) {
      const int kof = (kk * 32 + lg * 8) ^ psw;
      bf16x8 pa[2];
#pragma unroll
      for (int m = 0; m < 2; m++)
        pa[m] = *(const bf16x8*)&Ps[w][(m * 16 + li) * 128 + kof];
#pragma unroll
      for (int nd = 0; nd < 4; nd++) {
        bf16x8 vf = *(const bf16x8*)&Vs[(nd * 16 + li) * 128 + kof];
#pragma unroll
        for (int m = 0; m < 2; m++)
          acc_o[m][nd] = __builtin_amdgcn_mfma_f32_16x16x32_bf16(pa[m], vf, acc_o[m][nd], 0, 0, 0);
      }
    }
    __syncthreads();
  }

#pragma unroll
  for (int m = 0; m < 2; m++)
#pragma unroll
    for (int nd = 0; nd < 4; nd++)
#pragma unroll
      for (int j = 0; j < 4; j++) {
        int row = q0 + w * 32 + m * 16 + lg * 4 + j;
        int col = h * 64 + nd * 16 + li;
        float ov = acc_o[m][nd][j] / lrow[m][j];
        ctx[(basebs + row) * MODEL + col] = f2bf(ov);
      }
}

// ---------------- residual + LayerNorm ----------------
template <bool WB>
__global__ __launch_bounds__(256) void k_ln(const float* __restrict__ a,
                                            const float* __restrict__ bsrc,
                                            const float* __restrict__ gamma,
                                            const float* __restrict__ beta,
                                            float* __restrict__ outf,
                                            unsigned short* __restrict__ outb) {
  const int row = blockIdx.x;
  const int t = threadIdx.x;
  const size_t off = (size_t)row * MODEL + t * 4;
  float4 xa = *(const float4*)&a[off];
  float4 xb = *(const float4*)&bsrc[off];
  float z0 = xa.x + xb.x, z1 = xa.y + xb.y, z2 = xa.z + xb.z, z3 = xa.w + xb.w;
  float s = z0 + z1 + z2 + z3;
  float ss = z0 * z0 + z1 * z1 + z2 * z2 + z3 * z3;
#pragma unroll
  for (int o = 1; o < 64; o <<= 1) { s += __shfl_xor(s, o); ss += __shfl_xor(ss, o); }
  __shared__ float red[8];
  const int lane = t & 63, w = t >> 6;
  if (lane == 0) { red[w] = s; red[4 + w] = ss; }
  __syncthreads();
  s = red[0] + red[1] + red[2] + red[3];
  ss = red[4] + red[5] + red[6] + red[7];
  float mu = s * (1.f / MODEL);
  float var = ss * (1.f / MODEL) - mu * mu;
  float inv = rsqrtf(var + 1e-5f);
  float4 g = *(const float4*)&gamma[t * 4];
  float4 be = *(const float4*)&beta[t * 4];
  float o0 = (z0 - mu) * inv * g.x + be.x;
  float o1 = (z1 - mu) * inv * g.y + be.y;
  float o2 = (z2 - mu) * inv * g.z + be.z;
  float o3 = (z3 - mu) * inv * g.w + be.w;
  float4 ov = {o0, o1, o2, o3};
  *(float4*)&outf[off] = ov;
  if (WB) {
    ushort4v ob = {f2bf(o0), f2bf(o1), f2bf(o2), f2bf(o3)};
    *(ushort4v*)&outb[off] = ob;
  }
}

extern "C" void kernel_launch(void* const* d_in, const int* in_sizes, int n_in,
                              void* d_out, int out_size, void* d_ws, size_t ws_size,
                              hipStream_t stream) {
  (void)in_sizes; (void)n_in; (void)out_size; (void)ws_size;
  const float* x   = (const float*)d_in[0];
  const int*   mask= (const int*)d_in[1];
  const float* Wq  = (const float*)d_in[2];
  const float* bq  = (const float*)d_in[3];
  const float* Wk  = (const float*)d_in[4];
  const float* bk  = (const float*)d_in[5];
  const float* Wv  = (const float*)d_in[6];
  const float* bv  = (const float*)d_in[7];
  const float* Wo  = (const float*)d_in[8];
  const float* bo  = (const float*)d_in[9];
  const float* g1  = (const float*)d_in[10];
  const float* be1 = (const float*)d_in[11];
  const float* W1  = (const float*)d_in[12];
  const float* b1  = (const float*)d_in[13];
  const float* W2  = (const float*)d_in[14];
  const float* b2  = (const float*)d_in[15];
  const float* g2  = (const float*)d_in[16];
  const float* be2 = (const float*)d_in[17];
  float* out = (float*)d_out;

  char* p = (char*)d_ws;
  auto alloc = [&](size_t bytes) { char* r = p; p += (bytes + 255) & ~(size_t)255; return r; };
  unsigned short* xb   = (unsigned short*)alloc((size_t)MROWS * MODEL * 2);
  unsigned short* WqT  = (unsigned short*)alloc((size_t)MODEL * MODEL * 2);
  unsigned short* WkT  = (unsigned short*)alloc((size_t)MODEL * MODEL * 2);
  unsigned short* WvT  = (unsigned short*)alloc((size_t)MODEL * MODEL * 2);
  unsigned short* WoT  = (unsigned short*)alloc((size_t)MODEL * MODEL * 2);
  unsigned short* W1T  = (unsigned short*)alloc((size_t)MODEL * INNER * 2);
  unsigned short* W2T  = (unsigned short*)alloc((size_t)INNER * MODEL * 2);
  unsigned short* qb   = (unsigned short*)alloc((size_t)MROWS * MODEL * 2);
  unsigned short* kb   = (unsigned short*)alloc((size_t)MROWS * MODEL * 2);
  unsigned short* vtb  = (unsigned short*)alloc((size_t)MODEL * MROWS * 2);
  unsigned short* ctxb = (unsigned short*)alloc((size_t)MROWS * MODEL * 2);
  float* attn_out      = (float*)alloc((size_t)MROWS * MODEL * 4);
  float* y1f           = (float*)alloc((size_t)MROWS * MODEL * 4);
  unsigned short* y1b  = (unsigned short*)alloc((size_t)MROWS * MODEL * 2);
  // aliases over dead buffers:
  unsigned short* h1 = qb;        // [MROWS][INNER] bf16 = 64MB over qb..ctxb
  float* ff = attn_out;           // [MROWS][MODEL] fp32

  // convert & transpose
  k_cvt<<<(MROWS * MODEL / 4) / 256, 256, 0, stream>>>(x, xb, MROWS * MODEL / 4);
  k_transpose<<<dim3(MODEL / 32, MODEL / 32), 256, 0, stream>>>(Wq, WqT, MODEL, MODEL);
  k_transpose<<<dim3(MODEL / 32, MODEL / 32), 256, 0, stream>>>(Wk, WkT, MODEL, MODEL);
  k_transpose<<<dim3(MODEL / 32, MODEL / 32), 256, 0, stream>>>(Wv, WvT, MODEL, MODEL);
  k_transpose<<<dim3(MODEL / 32, MODEL / 32), 256, 0, stream>>>(Wo, WoT, MODEL, MODEL);
  k_transpose<<<dim3(INNER / 32, MODEL / 32), 256, 0, stream>>>(W1, W1T, MODEL, INNER);
  k_transpose<<<dim3(MODEL / 32, INNER / 32), 256, 0, stream>>>(W2, W2T, INNER, MODEL);

  // Q, K projections: [MROWS][MODEL]
  k_gemm<1, false><<<dim3(MODEL / 128, MROWS / 128), 256, 0, stream>>>(xb, WqT, bq, qb, MROWS, MODEL, MODEL);
  k_gemm<1, false><<<dim3(MODEL / 128, MROWS / 128), 256, 0, stream>>>(xb, WkT, bk, kb, MROWS, MODEL, MODEL);
  // V projection TRANSPOSED: Vt[n][m] = sum_k WvT[n][k] * xb[m][k]  -> [MODEL][MROWS]
  k_gemm<1, true><<<dim3(MROWS / 128, MODEL / 128), 256, 0, stream>>>(WvT, xb, bv, vtb, MODEL, MROWS, MODEL);

  // attention
  k_attn<<<dim3(SEQ / 128, BATCH * NHEADS), 256, 0, stream>>>(qb, kb, vtb, mask, ctxb);

  // output projection (fp32 out for residual)
  k_gemm<0, false><<<dim3(MODEL / 128, MROWS / 128), 256, 0, stream>>>(ctxb, WoT, bo, attn_out, MROWS, MODEL, MODEL);

  // LN1: y1 = LN(x + attn_out)
  k_ln<true><<<MROWS, 256, 0, stream>>>(x, attn_out, g1, be1, y1f, y1b);

  // FF1: h1 = relu(y1 @ W1 + b1)
  k_gemm<2, false><<<dim3(INNER / 128, MROWS / 128), 256, 0, stream>>>(y1b, W1T, b1, h1, MROWS, INNER, MODEL);

  // FF2: ff = h1 @ W2 + b2
  k_gemm<0, false><<<dim3(MODEL / 128, MROWS / 128), 256, 0, stream>>>(h1, W2T, b2, ff, MROWS, MODEL, INNER);

  // LN2 -> out
  k_ln<false><<<MROWS, 256, 0, stream>>>(y1f, ff, g2, be2, out, nullptr);
}

// Round 3
// 520.736 us; speedup vs baseline: 1.3724x; 1.3724x over previous
//
#include <hip/hip_runtime.h>
#include <stdint.h>

#define MODEL 1024
#define INNER 4096
#define NHEADS 16
#define HDIM 64
#define BATCH 4
#define SEQ 2048
#define MROWS (BATCH*SEQ)

typedef __bf16 bf16x8 __attribute__((ext_vector_type(8)));
typedef float f32x4 __attribute__((ext_vector_type(4)));
typedef unsigned short ushort4v __attribute__((ext_vector_type(4)));

__device__ __forceinline__ unsigned short f2bf(float f) {
  unsigned u = __builtin_bit_cast(unsigned, f);
  u += 0x7FFFu + ((u >> 16) & 1u);
  return (unsigned short)(u >> 16);
}

#define AS1 __attribute__((address_space(1)))
#define AS3 __attribute__((address_space(3)))
__device__ __forceinline__ void gload_lds16(const void* g, void* l) {
  __builtin_amdgcn_global_load_lds((const AS1 void*)g, (AS3 void*)l, 16, 0, 0);
}

// ---------------- fp32 -> bf16 convert (vectorized) ----------------
__global__ __launch_bounds__(256) void k_cvt(const float* __restrict__ in,
                                             unsigned short* __restrict__ out, int n4) {
  int i = blockIdx.x * 256 + threadIdx.x;
  if (i < n4) {
    float4 v = ((const float4*)in)[i];
    ushort4v o = { f2bf(v.x), f2bf(v.y), f2bf(v.z), f2bf(v.w) };
    ((ushort4v*)out)[i] = o;
  }
}

// ---------------- W [K][N] fp32 -> Wt [N][K] bf16 ----------------
__global__ __launch_bounds__(256) void k_transpose(const float* __restrict__ W,
                                                   unsigned short* __restrict__ Wt,
                                                   int K, int N) {
  __shared__ float tile[32][33];
  const int n0 = blockIdx.x * 32, k0 = blockIdx.y * 32;
  const int c = threadIdx.x & 31, r4 = threadIdx.x >> 5;
#pragma unroll
  for (int i = 0; i < 4; i++) {
    int r = r4 + i * 8;
    tile[r][c] = W[(size_t)(k0 + r) * N + n0 + c];
  }
  __syncthreads();
#pragma unroll
  for (int i = 0; i < 4; i++) {
    int r = r4 + i * 8;
    Wt[(size_t)(n0 + r) * K + k0 + c] = f2bf(tile[c][r]);
  }
}

// ---------------- GEMM: C[M][N] = A[M][K] * Bt[N][K]^T + bias ----------------
// OUTMODE: 0 = fp32, 1 = bf16, 2 = bf16 + relu.  BROW: bias indexed by row.
// 2-phase pipelined + bijective XCD-aware block swizzle (T1, m204 variant).
template <int OUTMODE, bool BROW>
__global__ __launch_bounds__(256) void k_gemm(const unsigned short* __restrict__ A,
                                              const unsigned short* __restrict__ Bt,
                                              const float* __restrict__ bias,
                                              void* __restrict__ Cout,
                                              int M, int N, int K) {
  __shared__ unsigned short As[2][128 * 32];
  __shared__ unsigned short Bs[2][128 * 32];
  const int t = threadIdx.x;
  const int lane = t & 63;
  const int w = t >> 6;
  const int li = lane & 15, lg = lane >> 4;

  // XCD-aware bijective swizzle of the linear block id
  const unsigned nwg = gridDim.x * gridDim.y;
  const unsigned lin = blockIdx.y * gridDim.x + blockIdx.x;
  const unsigned q8 = nwg >> 3, r8 = nwg & 7, xcd = lin & 7, pos = lin >> 3;
  const unsigned swz = (xcd < r8 ? xcd * (q8 + 1) : r8 * (q8 + 1) + (xcd - r8) * q8) + pos;
  const int bm = (swz / gridDim.x) * 128, bn = (swz % gridDim.x) * 128;

  const int wm = (w >> 1) * 64, wn = (w & 1) * 64;
  const int sc = (t & 3) * 8;
  const int sr = t >> 2;
  f32x4 acc[4][4] = {};
  const unsigned short* Abase = A + (size_t)(bm + sr) * K + sc;
  const unsigned short* Bbase = Bt + (size_t)(bn + sr) * K + sc;

  auto stage = [&](int buf, int k0) {
    gload_lds16(Abase + k0, &As[buf][w * 512]);
    gload_lds16(Abase + (size_t)64 * K + k0, &As[buf][2048 + w * 512]);
    gload_lds16(Bbase + k0, &Bs[buf][w * 512]);
    gload_lds16(Bbase + (size_t)64 * K + k0, &Bs[buf][2048 + w * 512]);
  };
  auto compute = [&](int buf) {
    bf16x8 a[4], b[4];
#pragma unroll
    for (int m = 0; m < 4; m++)
      a[m] = *(const bf16x8*)&As[buf][(wm + m * 16 + li) * 32 + lg * 8];
#pragma unroll
    for (int n = 0; n < 4; n++)
      b[n] = *(const bf16x8*)&Bs[buf][(wn + n * 16 + li) * 32 + lg * 8];
#pragma unroll
    for (int m = 0; m < 4; m++)
#pragma unroll
      for (int n = 0; n < 4; n++)
        acc[m][n] = __builtin_amdgcn_mfma_f32_16x16x32_bf16(a[m], b[n], acc[m][n], 0, 0, 0);
  };

  stage(0, 0);
  __syncthreads();
  int cur = 0;
  for (int k0 = 32; k0 < K; k0 += 32) {
    stage(cur ^ 1, k0);
    compute(cur);
    __syncthreads();
    cur ^= 1;
  }
  compute(cur);

#pragma unroll
  for (int m = 0; m < 4; m++) {
    const int row = bm + wm + m * 16 + lg * 4;
#pragma unroll
    for (int n = 0; n < 4; n++) {
      const int col = bn + wn + n * 16 + li;
      const float bvc = BROW ? 0.f : bias[col];
#pragma unroll
      for (int j = 0; j < 4; j++) {
        float v = acc[m][n][j] + (BROW ? bias[row + j] : bvc);
        if (OUTMODE == 2) v = fmaxf(v, 0.f);
        if (OUTMODE == 0)
          ((float*)Cout)[(size_t)(row + j) * N + col] = v;
        else
          ((unsigned short*)Cout)[(size_t)(row + j) * N + col] = f2bf(v);
      }
    }
  }
}

// ---------------- flash attention (swapped-operand, lane-local softmax) -----
// q,k: bf16 [B*S][MODEL] ; vt: bf16 [MODEL][B*S] ; ctx: bf16 [B*S][MODEL]
// S^T = mfma(K,Q): lane holds P[q=li][k in-lane] -> in-lane softmax (2 shfls).
// O^T = mfma(Vt,P): alpha/l lane-local; packed ushort4 epilogue.
// KVBLK=64, double-buffered K/V, prefetch-before-compute. LDS=48KB -> 3 blk/CU.
__global__ __launch_bounds__(256, 3) void k_attn(const unsigned short* __restrict__ q,
                                                 const unsigned short* __restrict__ kptr,
                                                 const unsigned short* __restrict__ vt,
                                                 const int* __restrict__ mask,
                                                 unsigned short* __restrict__ ctx) {
  __shared__ unsigned short Ks[2][64 * 64];   // [kv][d] rows 128B, col ^= 8*(kv&7)
  __shared__ unsigned short Vs[2][64 * 64];   // [d][kv] rows 128B, col ^= 8*(d&7)
  __shared__ unsigned short Ps[4][32 * 64];   // per-wave [q][kv], col ^= 8*(q&7)
  const int t = threadIdx.x, lane = t & 63, w = t >> 6;
  const int li = lane & 15, lg = lane >> 4;
  const int bh = blockIdx.y, b = bh >> 4, h = bh & 15;
  const int q0 = blockIdx.x * 128;
  const size_t basebs = (size_t)b * SEQ;
  const int sw = 8 * (li & 7);                 // read-side swizzle (elements)
  const int srow = lane >> 3;                  // staging row-within-8
  const int scsw = ((lane & 7) ^ srow) * 8;    // staging pre-swizzled source col

  auto stageKV = [&](int buf, int kt) {
#pragma unroll
    for (int i = 0; i < 2; i++) {
      const int row = i * 32 + w * 8 + srow;
      gload_lds16(kptr + (basebs + kt + row) * MODEL + h * 64 + scsw,
                  &Ks[buf][i * 2048 + w * 512]);
    }
#pragma unroll
    for (int i = 0; i < 2; i++) {
      const int row = i * 32 + w * 8 + srow;   // row = d
      gload_lds16(vt + (size_t)(h * 64 + row) * MROWS + basebs + kt + scsw,
                  &Vs[buf][i * 2048 + w * 512]);
    }
  };

  stageKV(0, 0);

  // Q fragments (B-operand): lane holds Q[q=li (per m)][d = kk*32+lg*8+j]
  bf16x8 qf[2][2];
#pragma unroll
  for (int m = 0; m < 2; m++)
#pragma unroll
    for (int kk = 0; kk < 2; kk++) {
      int row = q0 + w * 32 + m * 16 + li;
      qf[m][kk] = *(const bf16x8*)&q[(basebs + row) * MODEL + h * 64 + kk * 32 + lg * 8];
    }

  f32x4 acc_oT[4][2] = {};   // [nd][m]: O^T[d=nd*16+lg*4+j][q=m*16+li]
  float mrow[2] = {-3e38f, -3e38f}, lrow[2] = {0.f, 0.f};

  __syncthreads();

  int cur = 0;
  for (int kt = 0; kt < SEQ; kt += 64) {
    if (kt + 64 < SEQ) stageKV(cur ^ 1, kt + 64);

    int4 mk4[4];
#pragma unroll
    for (int n = 0; n < 4; n++)
      mk4[n] = *(const int4*)&mask[b * SEQ + kt + n * 16 + lg * 4];

    // S^T = K Q^T : sacc[m][n] holds P[q=li][kv = n*16+lg*4+j]
    f32x4 sacc[2][4] = {};
#pragma unroll
    for (int n = 0; n < 4; n++) {
      const int rb = (n * 16 + li) * 64;
      bf16x8 kf0 = *(const bf16x8*)&Ks[cur][rb + ((lg * 8) ^ sw)];
      bf16x8 kf1 = *(const bf16x8*)&Ks[cur][rb + ((32 + lg * 8) ^ sw)];
#pragma unroll
      for (int m = 0; m < 2; m++) {
        sacc[m][n] = __builtin_amdgcn_mfma_f32_16x16x32_bf16(kf0, qf[m][0], sacc[m][n], 0, 0, 0);
        sacc[m][n] = __builtin_amdgcn_mfma_f32_16x16x32_bf16(kf1, qf[m][1], sacc[m][n], 0, 0, 0);
      }
    }

    // lane-local online softmax (row q = li per m; k spread over lg -> 2 shfls)
#pragma unroll
    for (int m = 0; m < 2; m++) {
      float rmax = -3e38f;
#pragma unroll
      for (int n = 0; n < 4; n++) {
        const int mks[4] = {mk4[n].x, mk4[n].y, mk4[n].z, mk4[n].w};
#pragma unroll
        for (int j = 0; j < 4; j++) {
          float sv = sacc[m][n][j] * 0.125f;
          sv = (mks[j] == 0) ? -1e10f : sv;
          sacc[m][n][j] = sv;
          rmax = fmaxf(rmax, sv);
        }
      }
      rmax = fmaxf(rmax, __shfl_xor(rmax, 16));
      rmax = fmaxf(rmax, __shfl_xor(rmax, 32));
      float mnew = fmaxf(mrow[m], rmax);
      float alpha = __expf(mrow[m] - mnew);
      mrow[m] = mnew;
      float rsum = 0.f;
#pragma unroll
      for (int n = 0; n < 4; n++)
#pragma unroll
        for (int j = 0; j < 4; j++) {
          float pv = __expf(sacc[m][n][j] - mnew);
          sacc[m][n][j] = pv;
          rsum += pv;
        }
      rsum += __shfl_xor(rsum, 16);
      rsum += __shfl_xor(rsum, 32);
      lrow[m] = lrow[m] * alpha + rsum;
#pragma unroll
      for (int nd = 0; nd < 4; nd++)
#pragma unroll
        for (int j = 0; j < 4; j++) acc_oT[nd][m][j] *= alpha;
      // P -> LDS, vectorized b64 (j contiguous in k)
#pragma unroll
      for (int n = 0; n < 4; n++) {
        ushort4v pk = {f2bf(sacc[m][n][0]), f2bf(sacc[m][n][1]),
                       f2bf(sacc[m][n][2]), f2bf(sacc[m][n][3])};
        *(ushort4v*)&Ps[w][(m * 16 + li) * 64 + ((n * 16 + lg * 4) ^ sw)] = pk;
      }
    }

    // O^T += Vt * P  (A = Vt rows d, B = P rows q; all per-wave, compiler waits lgkm)
#pragma unroll
    for (int n2 = 0; n2 < 2; n2++) {
      const int kof = (n2 * 32 + lg * 8) ^ sw;
      bf16x8 pa0 = *(const bf16x8*)&Ps[w][li * 64 + kof];
      bf16x8 pa1 = *(const bf16x8*)&Ps[w][(16 + li) * 64 + kof];
#pragma unroll
      for (int nd = 0; nd < 4; nd++) {
        bf16x8 vfr = *(const bf16x8*)&Vs[cur][(nd * 16 + li) * 64 + kof];
        acc_oT[nd][0] = __builtin_amdgcn_mfma_f32_16x16x32_bf16(vfr, pa0, acc_oT[nd][0], 0, 0, 0);
        acc_oT[nd][1] = __builtin_amdgcn_mfma_f32_16x16x32_bf16(vfr, pa1, acc_oT[nd][1], 0, 0, 0);
      }
    }
    __syncthreads();
    cur ^= 1;
  }

  // epilogue: O[q][d] with q = li (lane-local l), d = nd*16+lg*4+j -> packed stores
#pragma unroll
  for (int m = 0; m < 2; m++) {
    const float rl = 1.f / lrow[m];
    const size_t rowoff = (basebs + q0 + w * 32 + m * 16 + li) * (size_t)MODEL + h * 64;
#pragma unroll
    for (int nd = 0; nd < 4; nd++) {
      ushort4v o = {f2bf(acc_oT[nd][m][0] * rl), f2bf(acc_oT[nd][m][1] * rl),
                    f2bf(acc_oT[nd][m][2] * rl), f2bf(acc_oT[nd][m][3] * rl)};
      *(ushort4v*)&ctx[rowoff + nd * 16 + lg * 4] = o;
    }
  }
}

// ---------------- residual + LayerNorm ----------------
template <bool WB>
__global__ __launch_bounds__(256) void k_ln(const float* __restrict__ a,
                                            const float* __restrict__ bsrc,
                                            const float* __restrict__ gamma,
                                            const float* __restrict__ beta,
                                            float* __restrict__ outf,
                                            unsigned short* __restrict__ outb) {
  const int row = blockIdx.x;
  const int t = threadIdx.x;
  const size_t off = (size_t)row * MODEL + t * 4;
  float4 xa = *(const float4*)&a[off];
  float4 xb = *(const float4*)&bsrc[off];
  float z0 = xa.x + xb.x, z1 = xa.y + xb.y, z2 = xa.z + xb.z, z3 = xa.w + xb.w;
  float s = z0 + z1 + z2 + z3;
  float ss = z0 * z0 + z1 * z1 + z2 * z2 + z3 * z3;
#pragma unroll
  for (int o = 1; o < 64; o <<= 1) { s += __shfl_xor(s, o); ss += __shfl_xor(ss, o); }
  __shared__ float red[8];
  const int lane = t & 63, w = t >> 6;
  if (lane == 0) { red[w] = s; red[4 + w] = ss; }
  __syncthreads();
  s = red[0] + red[1] + red[2] + red[3];
  ss = red[4] + red[5] + red[6] + red[7];
  float mu = s * (1.f / MODEL);
  float var = ss * (1.f / MODEL) - mu * mu;
  float inv = rsqrtf(var + 1e-5f);
  float4 g = *(const float4*)&gamma[t * 4];
  float4 be = *(const float4*)&beta[t * 4];
  float o0 = (z0 - mu) * inv * g.x + be.x;
  float o1 = (z1 - mu) * inv * g.y + be.y;
  float o2 = (z2 - mu) * inv * g.z + be.z;
  float o3 = (z3 - mu) * inv * g.w + be.w;
  float4 ov = {o0, o1, o2, o3};
  *(float4*)&outf[off] = ov;
  if (WB) {
    ushort4v ob = {f2bf(o0), f2bf(o1), f2bf(o2), f2bf(o3)};
    *(ushort4v*)&outb[off] = ob;
  }
}

extern "C" void kernel_launch(void* const* d_in, const int* in_sizes, int n_in,
                              void* d_out, int out_size, void* d_ws, size_t ws_size,
                              hipStream_t stream) {
  (void)in_sizes; (void)n_in; (void)out_size; (void)ws_size;
  const float* x   = (const float*)d_in[0];
  const int*   mask= (const int*)d_in[1];
  const float* Wq  = (const float*)d_in[2];
  const float* bq  = (const float*)d_in[3];
  const float* Wk  = (const float*)d_in[4];
  const float* bk  = (const float*)d_in[5];
  const float* Wv  = (const float*)d_in[6];
  const float* bv  = (const float*)d_in[7];
  const float* Wo  = (const float*)d_in[8];
  const float* bo  = (const float*)d_in[9];
  const float* g1  = (const float*)d_in[10];
  const float* be1 = (const float*)d_in[11];
  const float* W1  = (const float*)d_in[12];
  const float* b1  = (const float*)d_in[13];
  const float* W2  = (const float*)d_in[14];
  const float* b2  = (const float*)d_in[15];
  const float* g2  = (const float*)d_in[16];
  const float* be2 = (const float*)d_in[17];
  float* out = (float*)d_out;

  char* p = (char*)d_ws;
  auto alloc = [&](size_t bytes) { char* r = p; p += (bytes + 255) & ~(size_t)255; return r; };
  unsigned short* xb   = (unsigned short*)alloc((size_t)MROWS * MODEL * 2);
  unsigned short* WqT  = (unsigned short*)alloc((size_t)MODEL * MODEL * 2);
  unsigned short* WkT  = (unsigned short*)alloc((size_t)MODEL * MODEL * 2);
  unsigned short* WvT  = (unsigned short*)alloc((size_t)MODEL * MODEL * 2);
  unsigned short* WoT  = (unsigned short*)alloc((size_t)MODEL * MODEL * 2);
  unsigned short* W1T  = (unsigned short*)alloc((size_t)MODEL * INNER * 2);
  unsigned short* W2T  = (unsigned short*)alloc((size_t)INNER * MODEL * 2);
  unsigned short* qb   = (unsigned short*)alloc((size_t)MROWS * MODEL * 2);
  unsigned short* kb   = (unsigned short*)alloc((size_t)MROWS * MODEL * 2);
  unsigned short* vtb  = (unsigned short*)alloc((size_t)MODEL * MROWS * 2);
  unsigned short* ctxb = (unsigned short*)alloc((size_t)MROWS * MODEL * 2);
  float* attn_out      = (float*)alloc((size_t)MROWS * MODEL * 4);
  float* y1f           = (float*)alloc((size_t)MROWS * MODEL * 4);
  unsigned short* y1b  = (unsigned short*)alloc((size_t)MROWS * MODEL * 2);
  unsigned short* h1 = qb;        // [MROWS][INNER] bf16, aliases dead qb..ctxb
  float* ff = attn_out;           // [MROWS][MODEL] fp32

  k_cvt<<<(MROWS * MODEL / 4) / 256, 256, 0, stream>>>(x, xb, MROWS * MODEL / 4);
  k_transpose<<<dim3(MODEL / 32, MODEL / 32), 256, 0, stream>>>(Wq, WqT, MODEL, MODEL);
  k_transpose<<<dim3(MODEL / 32, MODEL / 32), 256, 0, stream>>>(Wk, WkT, MODEL, MODEL);
  k_transpose<<<dim3(MODEL / 32, MODEL / 32), 256, 0, stream>>>(Wv, WvT, MODEL, MODEL);
  k_transpose<<<dim3(MODEL / 32, MODEL / 32), 256, 0, stream>>>(Wo, WoT, MODEL, MODEL);
  k_transpose<<<dim3(INNER / 32, MODEL / 32), 256, 0, stream>>>(W1, W1T, MODEL, INNER);
  k_transpose<<<dim3(MODEL / 32, INNER / 32), 256, 0, stream>>>(W2, W2T, INNER, MODEL);

  k_gemm<1, false><<<dim3(MODEL / 128, MROWS / 128), 256, 0, stream>>>(xb, WqT, bq, qb, MROWS, MODEL, MODEL);
  k_gemm<1, false><<<dim3(MODEL / 128, MROWS / 128), 256, 0, stream>>>(xb, WkT, bk, kb, MROWS, MODEL, MODEL);
  // V projection transposed: vtb[n][m] = sum_k WvT[n][k]*xb[m][k] + bv[n]
  k_gemm<1, true><<<dim3(MROWS / 128, MODEL / 128), 256, 0, stream>>>(WvT, xb, bv, vtb, MODEL, MROWS, MODEL);

  k_attn<<<dim3(SEQ / 128, BATCH * NHEADS), 256, 0, stream>>>(qb, kb, vtb, mask, ctxb);

  k_gemm<0, false><<<dim3(MODEL / 128, MROWS / 128), 256, 0, stream>>>(ctxb, WoT, bo, attn_out, MROWS, MODEL, MODEL);

  k_ln<true><<<MROWS, 256, 0, stream>>>(x, attn_out, g1, be1, y1f, y1b);

  k_gemm<2, false><<<dim3(INNER / 128, MROWS / 128), 256, 0, stream>>>(y1b, W1T, b1, h1, MROWS, INNER, MODEL);

  k_gemm<0, false><<<dim3(MODEL / 128, MROWS / 128), 256, 0, stream>>>(h1, W2T, b2, ff, MROWS, MODEL, INNER);

  k_ln<false><<<MROWS, 256, 0, stream>>>(y1f, ff, g2, be2, out, nullptr);
}

// Round 4
// 514.597 us; speedup vs baseline: 1.3887x; 1.0119x over previous
//
#include <hip/hip_runtime.h>
#include <stdint.h>

#define MODEL 1024
#define INNER 4096
#define NHEADS 16
#define HDIM 64
#define BATCH 4
#define SEQ 2048
#define MROWS (BATCH*SEQ)

typedef __bf16 bf16x8 __attribute__((ext_vector_type(8)));
typedef float f32x4 __attribute__((ext_vector_type(4)));
typedef unsigned short ushort4v __attribute__((ext_vector_type(4)));

__device__ __forceinline__ unsigned short f2bf(float f) {
  unsigned u = __builtin_bit_cast(unsigned, f);
  u += 0x7FFFu + ((u >> 16) & 1u);
  return (unsigned short)(u >> 16);
}
// truncating pack of two floats -> two bf16 in one u32 (3 VALU ops)
__device__ __forceinline__ unsigned packbf_trunc(float lo, float hi) {
  return (__builtin_bit_cast(unsigned, hi) & 0xFFFF0000u) |
         (__builtin_bit_cast(unsigned, lo) >> 16);
}

#define AS1 __attribute__((address_space(1)))
#define AS3 __attribute__((address_space(3)))
__device__ __forceinline__ void gload_lds16(const void* g, void* l) {
  __builtin_amdgcn_global_load_lds((const AS1 void*)g, (AS3 void*)l, 16, 0, 0);
}

// ---------------- fp32 -> bf16 convert (vectorized) ----------------
__global__ __launch_bounds__(256) void k_cvt(const float* __restrict__ in,
                                             unsigned short* __restrict__ out, int n4) {
  int i = blockIdx.x * 256 + threadIdx.x;
  if (i < n4) {
    float4 v = ((const float4*)in)[i];
    ushort4v o = { f2bf(v.x), f2bf(v.y), f2bf(v.z), f2bf(v.w) };
    ((ushort4v*)out)[i] = o;
  }
}

// ---------------- W [K][N] fp32 -> Wt [N][K] bf16 ----------------
__global__ __launch_bounds__(256) void k_transpose(const float* __restrict__ W,
                                                   unsigned short* __restrict__ Wt,
                                                   int K, int N) {
  __shared__ float tile[32][33];
  const int n0 = blockIdx.x * 32, k0 = blockIdx.y * 32;
  const int c = threadIdx.x & 31, r4 = threadIdx.x >> 5;
#pragma unroll
  for (int i = 0; i < 4; i++) {
    int r = r4 + i * 8;
    tile[r][c] = W[(size_t)(k0 + r) * N + n0 + c];
  }
  __syncthreads();
#pragma unroll
  for (int i = 0; i < 4; i++) {
    int r = r4 + i * 8;
    Wt[(size_t)(n0 + r) * K + k0 + c] = f2bf(tile[c][r]);
  }
}

// ---------------- GEMM v3: C[M][N] = A[M][K]*Bt[N][K]^T + bias ----------------
// 256x128 tile, 8 waves (4M x 2N, 64x64 each), BK=32, 3 LDS buffers,
// depth-2 prefetch with counted vmcnt(3) + raw s_barrier (1 barrier/iter).
// LDS slot-swizzle: physical 16B slot p holds logical slot p ^ ((row>>1)&3),
// achieved by inverse-swizzling the global SOURCE column (gload_lds writes linear).
template <int OUTMODE, bool BROW>
__global__ __launch_bounds__(512, 4) void k_gemm(const unsigned short* __restrict__ A,
                                                 const unsigned short* __restrict__ Bt,
                                                 const float* __restrict__ bias,
                                                 void* __restrict__ Cout,
                                                 int M, int N, int K) {
  __shared__ unsigned short As[3][256 * 32];
  __shared__ unsigned short Bs[3][128 * 32];
  const int t = threadIdx.x;
  const int lane = t & 63;
  const int w = t >> 6;
  const int li = lane & 15, lg = lane >> 4;

  // XCD-aware bijective block swizzle
  const unsigned nwg = gridDim.x * gridDim.y;
  const unsigned lin = blockIdx.y * gridDim.x + blockIdx.x;
  const unsigned q8 = nwg >> 3, r8 = nwg & 7, xcd = lin & 7, pos = lin >> 3;
  const unsigned swz = (xcd < r8 ? xcd * (q8 + 1) : r8 * (q8 + 1) + (xcd - r8) * q8) + pos;
  const int bm = (swz / gridDim.x) * 256, bn = (swz % gridDim.x) * 128;

  const int wm4 = w >> 1, wn2 = w & 1;

  // staging: per-wave 16 rows per issue; lane -> (row = base + lane/4, slot = lane&3)
  const int rA0 = w * 16 + (lane >> 2);
  const int rA1 = 128 + rA0;
  const int slot = lane & 3;
  const unsigned short* a0 = A + (size_t)(bm + rA0) * K + (size_t)((slot ^ ((rA0 >> 1) & 3)) * 8);
  const unsigned short* a1 = A + (size_t)(bm + rA1) * K + (size_t)((slot ^ ((rA1 >> 1) & 3)) * 8);
  const unsigned short* b0 = Bt + (size_t)(bn + rA0) * K + (size_t)((slot ^ ((rA0 >> 1) & 3)) * 8);

  f32x4 acc[4][4] = {};
  const int NT = K / 32;

  auto stage = [&](int buf, int tt) {
    const int k0 = tt * 32;
    gload_lds16(a0 + k0, &As[buf][(w * 16) * 32]);
    gload_lds16(a1 + k0, &As[buf][(128 + w * 16) * 32]);
    gload_lds16(b0 + k0, &Bs[buf][(w * 16) * 32]);
  };

  stage(0, 0);
  stage(1, 1);
  int cur = 0;
  for (int tt = 0; tt < NT; ++tt) {
    asm volatile("s_waitcnt vmcnt(3)" ::: "memory");
    __builtin_amdgcn_s_barrier();
    int nb = cur + 2; if (nb >= 3) nb -= 3;
    if (tt + 2 < NT) stage(nb, tt + 2);
    bf16x8 a[4], b[4];
#pragma unroll
    for (int m = 0; m < 4; m++) {
      const int r = wm4 * 64 + m * 16 + li;
      a[m] = *(const bf16x8*)&As[cur][r * 32 + ((lg ^ ((r >> 1) & 3)) << 3)];
    }
#pragma unroll
    for (int n = 0; n < 4; n++) {
      const int r = wn2 * 64 + n * 16 + li;
      b[n] = *(const bf16x8*)&Bs[cur][r * 32 + ((lg ^ ((r >> 1) & 3)) << 3)];
    }
    __builtin_amdgcn_s_setprio(1);
#pragma unroll
    for (int m = 0; m < 4; m++)
#pragma unroll
      for (int n = 0; n < 4; n++)
        acc[m][n] = __builtin_amdgcn_mfma_f32_16x16x32_bf16(a[m], b[n], acc[m][n], 0, 0, 0);
    __builtin_amdgcn_s_setprio(0);
    __builtin_amdgcn_sched_barrier(0);
    cur = (cur == 2) ? 0 : cur + 1;
  }

#pragma unroll
  for (int m = 0; m < 4; m++) {
    const int row = bm + wm4 * 64 + m * 16 + lg * 4;
#pragma unroll
    for (int n = 0; n < 4; n++) {
      const int col = bn + wn2 * 64 + n * 16 + li;
      const float bvc = BROW ? 0.f : bias[col];
#pragma unroll
      for (int j = 0; j < 4; j++) {
        float v = acc[m][n][j] + (BROW ? bias[row + j] : bvc);
        if (OUTMODE == 2) v = fmaxf(v, 0.f);
        if (OUTMODE == 0)
          ((float*)Cout)[(size_t)(row + j) * N + col] = v;
        else
          ((unsigned short*)Cout)[(size_t)(row + j) * N + col] = f2bf(v);
      }
    }
  }
}

// ---------------- flash attention (counted-vmcnt pipeline) ----------------
// q,k: bf16 [B*S][MODEL] ; vt: bf16 [MODEL][B*S] ; ctx: bf16 [B*S][MODEL]
__global__ __launch_bounds__(256, 3) void k_attn(const unsigned short* __restrict__ q,
                                                 const unsigned short* __restrict__ kptr,
                                                 const unsigned short* __restrict__ vt,
                                                 const int* __restrict__ mask,
                                                 unsigned short* __restrict__ ctx) {
  __shared__ unsigned short Ks[2][64 * 64];
  __shared__ unsigned short Vs[2][64 * 64];
  __shared__ unsigned short Ps[4][32 * 64];
  const int t = threadIdx.x, lane = t & 63, w = t >> 6;
  const int li = lane & 15, lg = lane >> 4;
  const int bh = blockIdx.y, b = bh >> 4, h = bh & 15;
  const int q0 = blockIdx.x * 128;
  const size_t basebs = (size_t)b * SEQ;
  const int sw = 8 * (li & 7);
  const int srow = lane >> 3;
  const int scsw = ((lane & 7) ^ srow) * 8;

  auto stageKV = [&](int buf, int kt) {
#pragma unroll
    for (int i = 0; i < 2; i++) {
      const int row = i * 32 + w * 8 + srow;
      gload_lds16(kptr + (basebs + kt + row) * MODEL + h * 64 + scsw,
                  &Ks[buf][i * 2048 + w * 512]);
    }
#pragma unroll
    for (int i = 0; i < 2; i++) {
      const int row = i * 32 + w * 8 + srow;
      gload_lds16(vt + (size_t)(h * 64 + row) * MROWS + basebs + kt + scsw,
                  &Vs[buf][i * 2048 + w * 512]);
    }
  };

  stageKV(0, 0);

  bf16x8 qf[2][2];
#pragma unroll
  for (int m = 0; m < 2; m++)
#pragma unroll
    for (int kk = 0; kk < 2; kk++) {
      int row = q0 + w * 32 + m * 16 + li;
      qf[m][kk] = *(const bf16x8*)&q[(basebs + row) * MODEL + h * 64 + kk * 32 + lg * 8];
    }

  f32x4 acc_oT[4][2] = {};
  float mrow[2] = {-3e38f, -3e38f}, lrow[2] = {0.f, 0.f};

  int cur = 0;
  for (int kt = 0; kt < SEQ; kt += 64) {
    // mask loads FIRST so the compiler's wait for them doesn't drain the prefetch
    int4 mk4[4];
#pragma unroll
    for (int n = 0; n < 4; n++)
      mk4[n] = *(const int4*)&mask[b * SEQ + kt + n * 16 + lg * 4];

    const bool notlast = (kt + 64 < SEQ);
    if (notlast) {
      stageKV(cur ^ 1, kt + 64);
      asm volatile("s_waitcnt vmcnt(8)" ::: "memory");  // cur's 4 landed; mask4+next4 in flight
    } else {
      asm volatile("s_waitcnt vmcnt(4)" ::: "memory");  // cur's 4 landed; mask4 in flight
    }
    __builtin_amdgcn_s_barrier();

    // S^T = K Q^T : sacc[m][n] holds P[q=li][kv = n*16+lg*4+j]
    f32x4 sacc[2][4] = {};
#pragma unroll
    for (int n = 0; n < 4; n++) {
      const int rb = (n * 16 + li) * 64;
      bf16x8 kf0 = *(const bf16x8*)&Ks[cur][rb + ((lg * 8) ^ sw)];
      bf16x8 kf1 = *(const bf16x8*)&Ks[cur][rb + ((32 + lg * 8) ^ sw)];
#pragma unroll
      for (int m = 0; m < 2; m++) {
        sacc[m][n] = __builtin_amdgcn_mfma_f32_16x16x32_bf16(kf0, qf[m][0], sacc[m][n], 0, 0, 0);
        sacc[m][n] = __builtin_amdgcn_mfma_f32_16x16x32_bf16(kf1, qf[m][1], sacc[m][n], 0, 0, 0);
      }
    }

    // wave-uniform mask fast path (mask values are 0/1; AND==0 just takes slow path)
    int mand = mk4[0].x & mk4[0].y & mk4[0].z & mk4[0].w;
    mand &= mk4[1].x & mk4[1].y & mk4[1].z & mk4[1].w;
    mand &= mk4[2].x & mk4[2].y & mk4[2].z & mk4[2].w;
    mand &= mk4[3].x & mk4[3].y & mk4[3].z & mk4[3].w;
    const bool fast = __all(mand != 0);

#pragma unroll
    for (int m = 0; m < 2; m++) {
      float rmax = -3e38f;
      if (fast) {
#pragma unroll
        for (int n = 0; n < 4; n++)
#pragma unroll
          for (int j = 0; j < 4; j++) {
            float sv = sacc[m][n][j] * 0.125f;
            sacc[m][n][j] = sv;
            rmax = fmaxf(rmax, sv);
          }
      } else {
#pragma unroll
        for (int n = 0; n < 4; n++) {
          const int mks[4] = {mk4[n].x, mk4[n].y, mk4[n].z, mk4[n].w};
#pragma unroll
          for (int j = 0; j < 4; j++) {
            float sv = sacc[m][n][j] * 0.125f;
            sv = (mks[j] == 0) ? -1e10f : sv;
            sacc[m][n][j] = sv;
            rmax = fmaxf(rmax, sv);
          }
        }
      }
      rmax = fmaxf(rmax, __shfl_xor(rmax, 16));
      rmax = fmaxf(rmax, __shfl_xor(rmax, 32));
      // defer-max (T13): only rescale when the running max grew by > 8
      if (!__all(rmax <= mrow[m] + 8.f)) {
        float mnew = fmaxf(mrow[m], rmax);
        float alpha = __expf(mrow[m] - mnew);
        mrow[m] = mnew;
        lrow[m] *= alpha;
#pragma unroll
        for (int nd = 0; nd < 4; nd++)
#pragma unroll
          for (int j = 0; j < 4; j++) acc_oT[nd][m][j] *= alpha;
      }
      float rsum = 0.f;
#pragma unroll
      for (int n = 0; n < 4; n++)
#pragma unroll
        for (int j = 0; j < 4; j++) {
          float pv = __expf(sacc[m][n][j] - mrow[m]);
          sacc[m][n][j] = pv;
          rsum += pv;
        }
      rsum += __shfl_xor(rsum, 16);
      rsum += __shfl_xor(rsum, 32);
      lrow[m] += rsum;
      // P -> LDS, truncating pack (bounded by e^8; bf16 trunc err <0.4%)
#pragma unroll
      for (int n = 0; n < 4; n++) {
        uint2 pk = {packbf_trunc(sacc[m][n][0], sacc[m][n][1]),
                    packbf_trunc(sacc[m][n][2], sacc[m][n][3])};
        *(uint2*)&Ps[w][(m * 16 + li) * 64 + ((n * 16 + lg * 4) ^ sw)] = pk;
      }
    }
    asm volatile("s_waitcnt lgkmcnt(0)" ::: "memory");

    // O^T += Vt * P
#pragma unroll
    for (int n2 = 0; n2 < 2; n2++) {
      const int kof = (n2 * 32 + lg * 8) ^ sw;
      bf16x8 pa0 = *(const bf16x8*)&Ps[w][li * 64 + kof];
      bf16x8 pa1 = *(const bf16x8*)&Ps[w][(16 + li) * 64 + kof];
#pragma unroll
      for (int nd = 0; nd < 4; nd++) {
        bf16x8 vfr = *(const bf16x8*)&Vs[cur][(nd * 16 + li) * 64 + kof];
        acc_oT[nd][0] = __builtin_amdgcn_mfma_f32_16x16x32_bf16(vfr, pa0, acc_oT[nd][0], 0, 0, 0);
        acc_oT[nd][1] = __builtin_amdgcn_mfma_f32_16x16x32_bf16(vfr, pa1, acc_oT[nd][1], 0, 0, 0);
      }
    }
    __builtin_amdgcn_sched_barrier(0);
    __builtin_amdgcn_s_barrier();   // all waves done reading cur before next stage overwrites it
    cur ^= 1;
  }

#pragma unroll
  for (int m = 0; m < 2; m++) {
    const float rl = 1.f / lrow[m];
    const size_t rowoff = (basebs + q0 + w * 32 + m * 16 + li) * (size_t)MODEL + h * 64;
#pragma unroll
    for (int nd = 0; nd < 4; nd++) {
      ushort4v o = {f2bf(acc_oT[nd][m][0] * rl), f2bf(acc_oT[nd][m][1] * rl),
                    f2bf(acc_oT[nd][m][2] * rl), f2bf(acc_oT[nd][m][3] * rl)};
      *(ushort4v*)&ctx[rowoff + nd * 16 + lg * 4] = o;
    }
  }
}

// ---------------- residual + LayerNorm ----------------
template <bool WB>
__global__ __launch_bounds__(256) void k_ln(const float* __restrict__ a,
                                            const float* __restrict__ bsrc,
                                            const float* __restrict__ gamma,
                                            const float* __restrict__ beta,
                                            float* __restrict__ outf,
                                            unsigned short* __restrict__ outb) {
  const int row = blockIdx.x;
  const int t = threadIdx.x;
  const size_t off = (size_t)row * MODEL + t * 4;
  float4 xa = *(const float4*)&a[off];
  float4 xb = *(const float4*)&bsrc[off];
  float z0 = xa.x + xb.x, z1 = xa.y + xb.y, z2 = xa.z + xb.z, z3 = xa.w + xb.w;
  float s = z0 + z1 + z2 + z3;
  float ss = z0 * z0 + z1 * z1 + z2 * z2 + z3 * z3;
#pragma unroll
  for (int o = 1; o < 64; o <<= 1) { s += __shfl_xor(s, o); ss += __shfl_xor(ss, o); }
  __shared__ float red[8];
  const int lane = t & 63, w = t >> 6;
  if (lane == 0) { red[w] = s; red[4 + w] = ss; }
  __syncthreads();
  s = red[0] + red[1] + red[2] + red[3];
  ss = red[4] + red[5] + red[6] + red[7];
  float mu = s * (1.f / MODEL);
  float var = ss * (1.f / MODEL) - mu * mu;
  float inv = rsqrtf(var + 1e-5f);
  float4 g = *(const float4*)&gamma[t * 4];
  float4 be = *(const float4*)&beta[t * 4];
  float o0 = (z0 - mu) * inv * g.x + be.x;
  float o1 = (z1 - mu) * inv * g.y + be.y;
  float o2 = (z2 - mu) * inv * g.z + be.z;
  float o3 = (z3 - mu) * inv * g.w + be.w;
  float4 ov = {o0, o1, o2, o3};
  *(float4*)&outf[off] = ov;
  if (WB) {
    ushort4v ob = {f2bf(o0), f2bf(o1), f2bf(o2), f2bf(o3)};
    *(ushort4v*)&outb[off] = ob;
  }
}

extern "C" void kernel_launch(void* const* d_in, const int* in_sizes, int n_in,
                              void* d_out, int out_size, void* d_ws, size_t ws_size,
                              hipStream_t stream) {
  (void)in_sizes; (void)n_in; (void)out_size; (void)ws_size;
  const float* x   = (const float*)d_in[0];
  const int*   mask= (const int*)d_in[1];
  const float* Wq  = (const float*)d_in[2];
  const float* bq  = (const float*)d_in[3];
  const float* Wk  = (const float*)d_in[4];
  const float* bk  = (const float*)d_in[5];
  const float* Wv  = (const float*)d_in[6];
  const float* bv  = (const float*)d_in[7];
  const float* Wo  = (const float*)d_in[8];
  const float* bo  = (const float*)d_in[9];
  const float* g1  = (const float*)d_in[10];
  const float* be1 = (const float*)d_in[11];
  const float* W1  = (const float*)d_in[12];
  const float* b1  = (const float*)d_in[13];
  const float* W2  = (const float*)d_in[14];
  const float* b2  = (const float*)d_in[15];
  const float* g2  = (const float*)d_in[16];
  const float* be2 = (const float*)d_in[17];
  float* out = (float*)d_out;

  char* p = (char*)d_ws;
  auto alloc = [&](size_t bytes) { char* r = p; p += (bytes + 255) & ~(size_t)255; return r; };
  unsigned short* xb   = (unsigned short*)alloc((size_t)MROWS * MODEL * 2);
  unsigned short* WqT  = (unsigned short*)alloc((size_t)MODEL * MODEL * 2);
  unsigned short* WkT  = (unsigned short*)alloc((size_t)MODEL * MODEL * 2);
  unsigned short* WvT  = (unsigned short*)alloc((size_t)MODEL * MODEL * 2);
  unsigned short* WoT  = (unsigned short*)alloc((size_t)MODEL * MODEL * 2);
  unsigned short* W1T  = (unsigned short*)alloc((size_t)MODEL * INNER * 2);
  unsigned short* W2T  = (unsigned short*)alloc((size_t)INNER * MODEL * 2);
  unsigned short* qb   = (unsigned short*)alloc((size_t)MROWS * MODEL * 2);
  unsigned short* kb   = (unsigned short*)alloc((size_t)MROWS * MODEL * 2);
  unsigned short* vtb  = (unsigned short*)alloc((size_t)MODEL * MROWS * 2);
  unsigned short* ctxb = (unsigned short*)alloc((size_t)MROWS * MODEL * 2);
  float* attn_out      = (float*)alloc((size_t)MROWS * MODEL * 4);
  float* y1f           = (float*)alloc((size_t)MROWS * MODEL * 4);
  unsigned short* y1b  = (unsigned short*)alloc((size_t)MROWS * MODEL * 2);
  unsigned short* h1 = qb;        // [MROWS][INNER] bf16, aliases dead qb..ctxb
  float* ff = attn_out;           // [MROWS][MODEL] fp32

  k_cvt<<<(MROWS * MODEL / 4) / 256, 256, 0, stream>>>(x, xb, MROWS * MODEL / 4);
  k_transpose<<<dim3(MODEL / 32, MODEL / 32), 256, 0, stream>>>(Wq, WqT, MODEL, MODEL);
  k_transpose<<<dim3(MODEL / 32, MODEL / 32), 256, 0, stream>>>(Wk, WkT, MODEL, MODEL);
  k_transpose<<<dim3(MODEL / 32, MODEL / 32), 256, 0, stream>>>(Wv, WvT, MODEL, MODEL);
  k_transpose<<<dim3(MODEL / 32, MODEL / 32), 256, 0, stream>>>(Wo, WoT, MODEL, MODEL);
  k_transpose<<<dim3(INNER / 32, MODEL / 32), 256, 0, stream>>>(W1, W1T, MODEL, INNER);
  k_transpose<<<dim3(MODEL / 32, INNER / 32), 256, 0, stream>>>(W2, W2T, INNER, MODEL);

  // Q, K projections: [MROWS][MODEL]
  k_gemm<1, false><<<dim3(MODEL / 128, MROWS / 256), 512, 0, stream>>>(xb, WqT, bq, qb, MROWS, MODEL, MODEL);
  k_gemm<1, false><<<dim3(MODEL / 128, MROWS / 256), 512, 0, stream>>>(xb, WkT, bk, kb, MROWS, MODEL, MODEL);
  // V projection transposed: vtb[n][m] = sum_k WvT[n][k]*xb[m][k] + bv[n]
  k_gemm<1, true><<<dim3(MROWS / 128, MODEL / 256), 512, 0, stream>>>(WvT, xb, bv, vtb, MODEL, MROWS, MODEL);

  k_attn<<<dim3(SEQ / 128, BATCH * NHEADS), 256, 0, stream>>>(qb, kb, vtb, mask, ctxb);

  k_gemm<0, false><<<dim3(MODEL / 128, MROWS / 256), 512, 0, stream>>>(ctxb, WoT, bo, attn_out, MROWS, MODEL, MODEL);

  k_ln<true><<<MROWS, 256, 0, stream>>>(x, attn_out, g1, be1, y1f, y1b);

  k_gemm<2, false><<<dim3(INNER / 128, MROWS / 256), 512, 0, stream>>>(y1b, W1T, b1, h1, MROWS, INNER, MODEL);

  k_gemm<0, false><<<dim3(MODEL / 128, MROWS / 256), 512, 0, stream>>>(h1, W2T, b2, ff, MROWS, MODEL, INNER);

  k_ln<false><<<MROWS, 256, 0, stream>>>(y1f, ff, g2, be2, out, nullptr);
}

// Round 5
// 465.677 us; speedup vs baseline: 1.5346x; 1.1051x over previous
//
#include <hip/hip_runtime.h>
#include <stdint.h>

#define MODEL 1024
#define INNER 4096
#define NHEADS 16
#define HDIM 64
#define BATCH 4
#define SEQ 2048
#define MROWS (BATCH*SEQ)

typedef __bf16 bf16x8 __attribute__((ext_vector_type(8)));
typedef float f32x4 __attribute__((ext_vector_type(4)));
typedef unsigned short ushort4v __attribute__((ext_vector_type(4)));

__device__ __forceinline__ unsigned short f2bf(float f) {
  unsigned u = __builtin_bit_cast(unsigned, f);
  u += 0x7FFFu + ((u >> 16) & 1u);
  return (unsigned short)(u >> 16);
}
__device__ __forceinline__ unsigned packbf_trunc(float lo, float hi) {
  return (__builtin_bit_cast(unsigned, hi) & 0xFFFF0000u) |
         (__builtin_bit_cast(unsigned, lo) >> 16);
}

#define AS1 __attribute__((address_space(1)))
#define AS3 __attribute__((address_space(3)))
__device__ __forceinline__ void gload_lds16(const void* g, void* l) {
  __builtin_amdgcn_global_load_lds((const AS1 void*)g, (AS3 void*)l, 16, 0, 0);
}

// ---------------- fp32 -> bf16 convert ----------------
__global__ __launch_bounds__(256) void k_cvt(const float* __restrict__ in,
                                             unsigned short* __restrict__ out, int n4) {
  int i = blockIdx.x * 256 + threadIdx.x;
  if (i < n4) {
    float4 v = ((const float4*)in)[i];
    ushort4v o = { f2bf(v.x), f2bf(v.y), f2bf(v.z), f2bf(v.w) };
    ((ushort4v*)out)[i] = o;
  }
}

// ---------------- bias concat: bqkv = [bq|bk|bv] ----------------
__global__ __launch_bounds__(256) void k_bcat(const float* __restrict__ bq,
                                              const float* __restrict__ bk,
                                              const float* __restrict__ bv,
                                              float* __restrict__ o) {
  int i = blockIdx.x * 256 + threadIdx.x;
  o[i] = (i < 1024) ? bq[i] : (i < 2048) ? bk[i - 1024] : bv[i - 2048];
}

// ---------------- W [K][N] fp32 -> Wt [N][K] bf16 ----------------
__global__ __launch_bounds__(256) void k_transpose(const float* __restrict__ W,
                                                   unsigned short* __restrict__ Wt,
                                                   int K, int N) {
  __shared__ float tile[32][33];
  const int n0 = blockIdx.x * 32, k0 = blockIdx.y * 32;
  const int c = threadIdx.x & 31, r4 = threadIdx.x >> 5;
#pragma unroll
  for (int i = 0; i < 4; i++) {
    int r = r4 + i * 8;
    tile[r][c] = W[(size_t)(k0 + r) * N + n0 + c];
  }
  __syncthreads();
#pragma unroll
  for (int i = 0; i < 4; i++) {
    int r = r4 + i * 8;
    Wt[(size_t)(n0 + r) * K + k0 + c] = f2bf(tile[c][r]);
  }
}

// ============ GEMM: 256x256 tile, BK=32, 8 waves (2Mx4N, 128x64/wave) ============
// Phase-interleaved: per tile two phases {ds_read(8|4) ; stage 2 gload_lds ; barrier ;
// setprio(1) 16 MFMA setprio(0)}, boundary vmcnt(4) (never 0 until last) + barrier.
// 3 LDS buffers (96 KB): tile t reads buf t%3, tile t+2 staged into (t+2)%3 -> no WAR.
// Swizzle: physical 16B slot p of row r holds logical slot p^((r>>1)&3); source
// pre-swizzled (gload_lds writes linear), reads apply same involution.
// MODE: 0 = fp32 out (with SPLIT: grid.x doubled, partials to out0/out1, bias on half 0)
//       2 = bf16 + relu ; 3 = fused QKV (out0=q bf16, out1=k bf16, out2=v^T bf16)
template <int MODE, bool SPLIT>
__global__ __launch_bounds__(512, 2) void k_gemm(const unsigned short* __restrict__ A,
                                                 const unsigned short* __restrict__ Bt,
                                                 const float* __restrict__ bias,
                                                 void* __restrict__ out0,
                                                 void* __restrict__ out1,
                                                 void* __restrict__ out2,
                                                 int M, int N, int Kfull) {
  __shared__ unsigned short As[3 * 256 * 32];
  __shared__ unsigned short Bs[3 * 256 * 32];
  const int t = threadIdx.x;
  const int lane = t & 63;
  const int w = t >> 6;
  const int li = lane & 15, lg = lane >> 4;
  const int wm8 = w >> 2, wn4 = w & 3;  // wave tile: 128 rows x 64 cols

  // XCD-aware bijective block swizzle
  const unsigned nwg = gridDim.x * gridDim.y;
  const unsigned lin = blockIdx.y * gridDim.x + blockIdx.x;
  const unsigned q8 = nwg >> 3, r8 = nwg & 7, xcd = lin & 7, pos = lin >> 3;
  const unsigned swz = (xcd < r8 ? xcd * (q8 + 1) : r8 * (q8 + 1) + (xcd - r8) * q8) + pos;
  int bx = swz % gridDim.x, by = swz / gridDim.x;

  int kp = 0, Ksub = Kfull;
  if (SPLIT) {
    const int hx = gridDim.x >> 1;
    kp = bx >= hx;
    bx -= kp * hx;
    Ksub = Kfull >> 1;
  }
  const int bm = by * 256, bn = bx * 256;
  const size_t koff = (size_t)kp * Ksub;
  const int NT = Ksub / 32;

  // staging geometry: 4 gloads/thread/tile (2 A + 2 B), rows sr0 and sr0+128
  const int sr0 = w * 16 + (lane >> 2);
  const int sr1 = sr0 + 128;
  const int sl = lane & 3;
  const unsigned short* pA0 = A + (size_t)(bm + sr0) * Kfull + koff + ((sl ^ ((sr0 >> 1) & 3)) << 3);
  const unsigned short* pA1 = A + (size_t)(bm + sr1) * Kfull + koff + ((sl ^ ((sr1 >> 1) & 3)) << 3);
  const unsigned short* pB0 = Bt + (size_t)(bn + sr0) * Kfull + koff + ((sl ^ ((sr0 >> 1) & 3)) << 3);
  const unsigned short* pB1 = Bt + (size_t)(bn + sr1) * Kfull + koff + ((sl ^ ((sr1 >> 1) & 3)) << 3);

  f32x4 acc[8][4] = {};

  auto stageA = [&](int buf, int tt) {
    gload_lds16(pA0 + tt * 32, &As[buf * 8192 + w * 512]);
    gload_lds16(pA1 + tt * 32, &As[buf * 8192 + 4096 + w * 512]);
  };
  auto stageB = [&](int buf, int tt) {
    gload_lds16(pB0 + tt * 32, &Bs[buf * 8192 + w * 512]);
    gload_lds16(pB1 + tt * 32, &Bs[buf * 8192 + 4096 + w * 512]);
  };

  // prologue: tiles 0,1 fully staged; wait tile0 (4 younger in flight), barrier
  stageA(0, 0); stageB(0, 0);
  stageA(1, 1); stageB(1, 1);
  asm volatile("s_waitcnt vmcnt(4)" ::: "memory");
  __builtin_amdgcn_s_barrier();

  int buf = 0;
  for (int tt = 0; tt < NT; ++tt) {
    const int nb = (buf + 2 >= 3) ? buf - 1 : buf + 2;
    const unsigned short* Ab = &As[buf * 8192];
    const unsigned short* Bb = &Bs[buf * 8192];
    // ---- phase A: read a[0:4] + b[0:4], stage A-half of tile tt+2 ----
    bf16x8 av[4], bv_[4];
#pragma unroll
    for (int m = 0; m < 4; m++) {
      const int r = wm8 * 128 + m * 16 + li;
      av[m] = *(const bf16x8*)&Ab[r * 32 + ((lg ^ ((r >> 1) & 3)) << 3)];
    }
#pragma unroll
    for (int n = 0; n < 4; n++) {
      const int r = wn4 * 64 + n * 16 + li;
      bv_[n] = *(const bf16x8*)&Bb[r * 32 + ((lg ^ ((r >> 1) & 3)) << 3)];
    }
    if (tt + 2 < NT) stageA(nb, tt + 2);
    __builtin_amdgcn_s_barrier();
    __builtin_amdgcn_s_setprio(1);
#pragma unroll
    for (int m = 0; m < 4; m++)
#pragma unroll
      for (int n = 0; n < 4; n++)
        acc[m][n] = __builtin_amdgcn_mfma_f32_16x16x32_bf16(av[m], bv_[n], acc[m][n], 0, 0, 0);
    __builtin_amdgcn_s_setprio(0);
    // ---- phase B: read a[4:8], stage B-half of tile tt+2 ----
    bf16x8 av2[4];
#pragma unroll
    for (int m = 0; m < 4; m++) {
      const int r = wm8 * 128 + 64 + m * 16 + li;
      av2[m] = *(const bf16x8*)&Ab[r * 32 + ((lg ^ ((r >> 1) & 3)) << 3)];
    }
    if (tt + 2 < NT) stageB(nb, tt + 2);
    __builtin_amdgcn_s_barrier();
    __builtin_amdgcn_s_setprio(1);
#pragma unroll
    for (int m = 0; m < 4; m++)
#pragma unroll
      for (int n = 0; n < 4; n++)
        acc[m + 4][n] = __builtin_amdgcn_mfma_f32_16x16x32_bf16(av2[m], bv_[n], acc[m + 4][n], 0, 0, 0);
    __builtin_amdgcn_s_setprio(0);
    // ---- boundary: next tile's 4 loads retired; tile tt+2's 4 may stay in flight ----
    if (tt + 2 < NT) asm volatile("s_waitcnt vmcnt(4)" ::: "memory");
    else             asm volatile("s_waitcnt vmcnt(0)" ::: "memory");
    __builtin_amdgcn_s_barrier();
    buf = (buf == 2) ? 0 : buf + 1;
  }

  // ---------------- epilogue ----------------
#pragma unroll
  for (int m = 0; m < 8; m++) {
    const int row0 = bm + wm8 * 128 + m * 16 + lg * 4;
#pragma unroll
    for (int n = 0; n < 4; n++) {
      const int gcol = bn + wn4 * 64 + n * 16 + li;
      if (MODE == 0) {
        float* dst = (float*)(kp ? out1 : out0);
        const float bvc = (!SPLIT || kp == 0) ? bias[gcol] : 0.f;
#pragma unroll
        for (int j = 0; j < 4; j++)
          dst[(size_t)(row0 + j) * N + gcol] = acc[m][n][j] + bvc;
      } else if (MODE == 2) {
        const float bvc = bias[gcol];
#pragma unroll
        for (int j = 0; j < 4; j++)
          ((unsigned short*)out0)[(size_t)(row0 + j) * N + gcol] = f2bf(fmaxf(acc[m][n][j] + bvc, 0.f));
      } else {  // MODE 3: fused QKV
        const float bvc = bias[gcol];
        const int region = gcol >> 10, lcol = gcol & 1023;
        if (region < 2) {
          unsigned short* dst = (unsigned short*)(region ? out1 : out0);
#pragma unroll
          for (int j = 0; j < 4; j++)
            dst[(size_t)(row0 + j) * MODEL + lcol] = f2bf(acc[m][n][j] + bvc);
        } else {
          ushort4v o = {f2bf(acc[m][n][0] + bvc), f2bf(acc[m][n][1] + bvc),
                        f2bf(acc[m][n][2] + bvc), f2bf(acc[m][n][3] + bvc)};
          *(ushort4v*)&((unsigned short*)out2)[(size_t)lcol * MROWS + row0] = o;
        }
      }
    }
  }
}

// ---------------- flash attention (unchanged from round 4) ----------------
__global__ __launch_bounds__(256, 3) void k_attn(const unsigned short* __restrict__ q,
                                                 const unsigned short* __restrict__ kptr,
                                                 const unsigned short* __restrict__ vt,
                                                 const int* __restrict__ mask,
                                                 unsigned short* __restrict__ ctx) {
  __shared__ unsigned short Ks[2][64 * 64];
  __shared__ unsigned short Vs[2][64 * 64];
  __shared__ unsigned short Ps[4][32 * 64];
  const int t = threadIdx.x, lane = t & 63, w = t >> 6;
  const int li = lane & 15, lg = lane >> 4;
  const int bh = blockIdx.y, b = bh >> 4, h = bh & 15;
  const int q0 = blockIdx.x * 128;
  const size_t basebs = (size_t)b * SEQ;
  const int sw = 8 * (li & 7);
  const int srow = lane >> 3;
  const int scsw = ((lane & 7) ^ srow) * 8;

  auto stageKV = [&](int buf, int kt) {
#pragma unroll
    for (int i = 0; i < 2; i++) {
      const int row = i * 32 + w * 8 + srow;
      gload_lds16(kptr + (basebs + kt + row) * MODEL + h * 64 + scsw,
                  &Ks[buf][i * 2048 + w * 512]);
    }
#pragma unroll
    for (int i = 0; i < 2; i++) {
      const int row = i * 32 + w * 8 + srow;
      gload_lds16(vt + (size_t)(h * 64 + row) * MROWS + basebs + kt + scsw,
                  &Vs[buf][i * 2048 + w * 512]);
    }
  };

  stageKV(0, 0);

  bf16x8 qf[2][2];
#pragma unroll
  for (int m = 0; m < 2; m++)
#pragma unroll
    for (int kk = 0; kk < 2; kk++) {
      int row = q0 + w * 32 + m * 16 + li;
      qf[m][kk] = *(const bf16x8*)&q[(basebs + row) * MODEL + h * 64 + kk * 32 + lg * 8];
    }

  f32x4 acc_oT[4][2] = {};
  float mrow[2] = {-3e38f, -3e38f}, lrow[2] = {0.f, 0.f};

  int cur = 0;
  for (int kt = 0; kt < SEQ; kt += 64) {
    int4 mk4[4];
#pragma unroll
    for (int n = 0; n < 4; n++)
      mk4[n] = *(const int4*)&mask[b * SEQ + kt + n * 16 + lg * 4];

    const bool notlast = (kt + 64 < SEQ);
    if (notlast) {
      stageKV(cur ^ 1, kt + 64);
      asm volatile("s_waitcnt vmcnt(8)" ::: "memory");
    } else {
      asm volatile("s_waitcnt vmcnt(4)" ::: "memory");
    }
    __builtin_amdgcn_s_barrier();

    f32x4 sacc[2][4] = {};
#pragma unroll
    for (int n = 0; n < 4; n++) {
      const int rb = (n * 16 + li) * 64;
      bf16x8 kf0 = *(const bf16x8*)&Ks[cur][rb + ((lg * 8) ^ sw)];
      bf16x8 kf1 = *(const bf16x8*)&Ks[cur][rb + ((32 + lg * 8) ^ sw)];
#pragma unroll
      for (int m = 0; m < 2; m++) {
        sacc[m][n] = __builtin_amdgcn_mfma_f32_16x16x32_bf16(kf0, qf[m][0], sacc[m][n], 0, 0, 0);
        sacc[m][n] = __builtin_amdgcn_mfma_f32_16x16x32_bf16(kf1, qf[m][1], sacc[m][n], 0, 0, 0);
      }
    }

    int mand = mk4[0].x & mk4[0].y & mk4[0].z & mk4[0].w;
    mand &= mk4[1].x & mk4[1].y & mk4[1].z & mk4[1].w;
    mand &= mk4[2].x & mk4[2].y & mk4[2].z & mk4[2].w;
    mand &= mk4[3].x & mk4[3].y & mk4[3].z & mk4[3].w;
    const bool fast = __all(mand != 0);

#pragma unroll
    for (int m = 0; m < 2; m++) {
      float rmax = -3e38f;
      if (fast) {
#pragma unroll
        for (int n = 0; n < 4; n++)
#pragma unroll
          for (int j = 0; j < 4; j++) {
            float sv = sacc[m][n][j] * 0.125f;
            sacc[m][n][j] = sv;
            rmax = fmaxf(rmax, sv);
          }
      } else {
#pragma unroll
        for (int n = 0; n < 4; n++) {
          const int mks[4] = {mk4[n].x, mk4[n].y, mk4[n].z, mk4[n].w};
#pragma unroll
          for (int j = 0; j < 4; j++) {
            float sv = sacc[m][n][j] * 0.125f;
            sv = (mks[j] == 0) ? -1e10f : sv;
            sacc[m][n][j] = sv;
            rmax = fmaxf(rmax, sv);
          }
        }
      }
      rmax = fmaxf(rmax, __shfl_xor(rmax, 16));
      rmax = fmaxf(rmax, __shfl_xor(rmax, 32));
      if (!__all(rmax <= mrow[m] + 8.f)) {
        float mnew = fmaxf(mrow[m], rmax);
        float alpha = __expf(mrow[m] - mnew);
        mrow[m] = mnew;
        lrow[m] *= alpha;
#pragma unroll
        for (int nd = 0; nd < 4; nd++)
#pragma unroll
          for (int j = 0; j < 4; j++) acc_oT[nd][m][j] *= alpha;
      }
      float rsum = 0.f;
#pragma unroll
      for (int n = 0; n < 4; n++)
#pragma unroll
        for (int j = 0; j < 4; j++) {
          float pv = __expf(sacc[m][n][j] - mrow[m]);
          sacc[m][n][j] = pv;
          rsum += pv;
        }
      rsum += __shfl_xor(rsum, 16);
      rsum += __shfl_xor(rsum, 32);
      lrow[m] += rsum;
#pragma unroll
      for (int n = 0; n < 4; n++) {
        uint2 pk = {packbf_trunc(sacc[m][n][0], sacc[m][n][1]),
                    packbf_trunc(sacc[m][n][2], sacc[m][n][3])};
        *(uint2*)&Ps[w][(m * 16 + li) * 64 + ((n * 16 + lg * 4) ^ sw)] = pk;
      }
    }
    asm volatile("s_waitcnt lgkmcnt(0)" ::: "memory");

#pragma unroll
    for (int n2 = 0; n2 < 2; n2++) {
      const int kof = (n2 * 32 + lg * 8) ^ sw;
      bf16x8 pa0 = *(const bf16x8*)&Ps[w][li * 64 + kof];
      bf16x8 pa1 = *(const bf16x8*)&Ps[w][(16 + li) * 64 + kof];
#pragma unroll
      for (int nd = 0; nd < 4; nd++) {
        bf16x8 vfr = *(const bf16x8*)&Vs[cur][(nd * 16 + li) * 64 + kof];
        acc_oT[nd][0] = __builtin_amdgcn_mfma_f32_16x16x32_bf16(vfr, pa0, acc_oT[nd][0], 0, 0, 0);
        acc_oT[nd][1] = __builtin_amdgcn_mfma_f32_16x16x32_bf16(vfr, pa1, acc_oT[nd][1], 0, 0, 0);
      }
    }
    __builtin_amdgcn_sched_barrier(0);
    __builtin_amdgcn_s_barrier();
    cur ^= 1;
  }

#pragma unroll
  for (int m = 0; m < 2; m++) {
    const float rl = 1.f / lrow[m];
    const size_t rowoff = (basebs + q0 + w * 32 + m * 16 + li) * (size_t)MODEL + h * 64;
#pragma unroll
    for (int nd = 0; nd < 4; nd++) {
      ushort4v o = {f2bf(acc_oT[nd][m][0] * rl), f2bf(acc_oT[nd][m][1] * rl),
                    f2bf(acc_oT[nd][m][2] * rl), f2bf(acc_oT[nd][m][3] * rl)};
      *(ushort4v*)&ctx[rowoff + nd * 16 + lg * 4] = o;
    }
  }
}

// ---------------- residual + residual + LayerNorm (3 input streams) ----------------
template <bool WB>
__global__ __launch_bounds__(256) void k_ln3(const float* __restrict__ a,
                                             const float* __restrict__ b0,
                                             const float* __restrict__ b1,
                                             const float* __restrict__ gamma,
                                             const float* __restrict__ beta,
                                             float* __restrict__ outf,
                                             unsigned short* __restrict__ outb) {
  const int row = blockIdx.x;
  const int t = threadIdx.x;
  const size_t off = (size_t)row * MODEL + t * 4;
  float4 xa = *(const float4*)&a[off];
  float4 x0 = *(const float4*)&b0[off];
  float4 x1 = *(const float4*)&b1[off];
  float z0 = xa.x + x0.x + x1.x, z1 = xa.y + x0.y + x1.y;
  float z2 = xa.z + x0.z + x1.z, z3 = xa.w + x0.w + x1.w;
  float s = z0 + z1 + z2 + z3;
  float ss = z0 * z0 + z1 * z1 + z2 * z2 + z3 * z3;
#pragma unroll
  for (int o = 1; o < 64; o <<= 1) { s += __shfl_xor(s, o); ss += __shfl_xor(ss, o); }
  __shared__ float red[8];
  const int lane = t & 63, w = t >> 6;
  if (lane == 0) { red[w] = s; red[4 + w] = ss; }
  __syncthreads();
  s = red[0] + red[1] + red[2] + red[3];
  ss = red[4] + red[5] + red[6] + red[7];
  float mu = s * (1.f / MODEL);
  float var = ss * (1.f / MODEL) - mu * mu;
  float inv = rsqrtf(var + 1e-5f);
  float4 g = *(const float4*)&gamma[t * 4];
  float4 be = *(const float4*)&beta[t * 4];
  float o0 = (z0 - mu) * inv * g.x + be.x;
  float o1 = (z1 - mu) * inv * g.y + be.y;
  float o2 = (z2 - mu) * inv * g.z + be.z;
  float o3 = (z3 - mu) * inv * g.w + be.w;
  float4 ov = {o0, o1, o2, o3};
  *(float4*)&outf[off] = ov;
  if (WB) {
    ushort4v ob = {f2bf(o0), f2bf(o1), f2bf(o2), f2bf(o3)};
    *(ushort4v*)&outb[off] = ob;
  }
}

extern "C" void kernel_launch(void* const* d_in, const int* in_sizes, int n_in,
                              void* d_out, int out_size, void* d_ws, size_t ws_size,
                              hipStream_t stream) {
  (void)in_sizes; (void)n_in; (void)out_size; (void)ws_size;
  const float* x   = (const float*)d_in[0];
  const int*   mask= (const int*)d_in[1];
  const float* Wq  = (const float*)d_in[2];
  const float* bq  = (const float*)d_in[3];
  const float* Wk  = (const float*)d_in[4];
  const float* bk  = (const float*)d_in[5];
  const float* Wv  = (const float*)d_in[6];
  const float* bv  = (const float*)d_in[7];
  const float* Wo  = (const float*)d_in[8];
  const float* bo  = (const float*)d_in[9];
  const float* g1  = (const float*)d_in[10];
  const float* be1 = (const float*)d_in[11];
  const float* W1  = (const float*)d_in[12];
  const float* b1  = (const float*)d_in[13];
  const float* W2  = (const float*)d_in[14];
  const float* b2  = (const float*)d_in[15];
  const float* g2  = (const float*)d_in[16];
  const float* be2 = (const float*)d_in[17];
  float* out = (float*)d_out;

  char* p = (char*)d_ws;
  auto alloc = [&](size_t bytes) { char* r = p; p += (bytes + 255) & ~(size_t)255; return r; };
  // order matters for aliasing below
  unsigned short* xb    = (unsigned short*)alloc((size_t)MROWS * MODEL * 2);   // 16MB
  unsigned short* y1b   = (unsigned short*)alloc((size_t)MROWS * MODEL * 2);   // 16MB
  unsigned short* WqkvT = (unsigned short*)alloc((size_t)3 * MODEL * MODEL * 2); // 6MB
  unsigned short* WoT   = (unsigned short*)alloc((size_t)MODEL * MODEL * 2);
  unsigned short* W1T   = (unsigned short*)alloc((size_t)MODEL * INNER * 2);
  unsigned short* W2T   = (unsigned short*)alloc((size_t)INNER * MODEL * 2);
  float* bqkv           = (float*)alloc(3072 * 4);
  unsigned short* qb    = (unsigned short*)alloc((size_t)MROWS * MODEL * 2);   // 16MB
  unsigned short* kb    = (unsigned short*)alloc((size_t)MROWS * MODEL * 2);   // 16MB
  unsigned short* vtb   = (unsigned short*)alloc((size_t)MODEL * MROWS * 2);   // 16MB
  unsigned short* ctxb  = (unsigned short*)alloc((size_t)MROWS * MODEL * 2);   // 16MB
  float* attn_out       = (float*)alloc((size_t)MROWS * MODEL * 4);            // 32MB
  float* y1f            = (float*)alloc((size_t)MROWS * MODEL * 4);            // 32MB
  // aliases over dead buffers:
  unsigned short* h1 = qb;          // FF1 out [MROWS][INNER] bf16 = 64MB over qb..ctxb
  float* p1wo = (float*)kb;         // Wo split-K partial 1: 32MB over kb+vtb (dead after attn)
  float* ff   = attn_out;           // FF2 partial 0 (attn_out dead after LN1)
  float* p1ff = (float*)xb;         // FF2 partial 1: 32MB over xb+y1b (dead after FF1)

  k_cvt<<<(MROWS * MODEL / 4) / 256, 256, 0, stream>>>(x, xb, MROWS * MODEL / 4);
  k_bcat<<<12, 256, 0, stream>>>(bq, bk, bv, bqkv);
  k_transpose<<<dim3(MODEL / 32, MODEL / 32), 256, 0, stream>>>(Wq, WqkvT, MODEL, MODEL);
  k_transpose<<<dim3(MODEL / 32, MODEL / 32), 256, 0, stream>>>(Wk, WqkvT + (size_t)MODEL * MODEL, MODEL, MODEL);
  k_transpose<<<dim3(MODEL / 32, MODEL / 32), 256, 0, stream>>>(Wv, WqkvT + (size_t)2 * MODEL * MODEL, MODEL, MODEL);
  k_transpose<<<dim3(MODEL / 32, MODEL / 32), 256, 0, stream>>>(Wo, WoT, MODEL, MODEL);
  k_transpose<<<dim3(INNER / 32, MODEL / 32), 256, 0, stream>>>(W1, W1T, MODEL, INNER);
  k_transpose<<<dim3(MODEL / 32, INNER / 32), 256, 0, stream>>>(W2, W2T, INNER, MODEL);

  // fused QKV: C[8192][3072]; Q,K -> [row][col] bf16 ; V -> transposed [col][row]
  k_gemm<3, false><<<dim3(12, MROWS / 256), 512, 0, stream>>>(xb, WqkvT, bqkv, qb, kb, vtb, MROWS, 3072, MODEL);

  k_attn<<<dim3(SEQ / 128, BATCH * NHEADS), 256, 0, stream>>>(qb, kb, vtb, mask, ctxb);

  // Wo projection, split-K x2 folded into grid.x (full-GPU): partials attn_out + p1wo
  k_gemm<0, true><<<dim3(8, MROWS / 256), 512, 0, stream>>>(ctxb, WoT, bo, attn_out, p1wo, nullptr, MROWS, MODEL, MODEL);

  // LN1: y1 = LN(x + attn_out + p1wo)
  k_ln3<true><<<MROWS, 256, 0, stream>>>(x, attn_out, p1wo, g1, be1, y1f, y1b);

  // FF1: h1 = relu(y1 @ W1 + b1)
  k_gemm<2, false><<<dim3(INNER / 256, MROWS / 256), 512, 0, stream>>>(y1b, W1T, b1, h1, nullptr, nullptr, MROWS, INNER, MODEL);

  // FF2 split-K x2: partials ff + p1ff
  k_gemm<0, true><<<dim3(8, MROWS / 256), 512, 0, stream>>>(h1, W2T, b2, ff, p1ff, nullptr, MROWS, MODEL, INNER);

  // LN2 -> out
  k_ln3<false><<<MROWS, 256, 0, stream>>>(y1f, ff, p1ff, g2, be2, out, nullptr);
}

// Round 6
// 457.171 us; speedup vs baseline: 1.5632x; 1.0186x over previous
//
#include <hip/hip_runtime.h>
#include <stdint.h>

#define MODEL 1024
#define INNER 4096
#define NHEADS 16
#define HDIM 64
#define BATCH 4
#define SEQ 2048
#define MROWS (BATCH*SEQ)

// Q is pre-scaled by 1/sqrt(HDIM) * log2(e) at the QKV epilogue, so QK^T
// lands directly in the exp2 domain.
#define QSCALE 0.18033688011112042f   // 0.125 * log2(e)
#define DEFER_THR 11.541560327111708f // 8 * log2(e)

typedef __bf16 bf16x8 __attribute__((ext_vector_type(8)));
typedef float f32x4 __attribute__((ext_vector_type(4)));
typedef unsigned short ushort4v __attribute__((ext_vector_type(4)));

extern "C" __device__ float __ocml_native_exp2_f32(float);

__device__ __forceinline__ unsigned short f2bf(float f) {
  unsigned u = __builtin_bit_cast(unsigned, f);
  u += 0x7FFFu + ((u >> 16) & 1u);
  return (unsigned short)(u >> 16);
}
__device__ __forceinline__ unsigned packbf_trunc(float lo, float hi) {
  return (__builtin_bit_cast(unsigned, hi) & 0xFFFF0000u) |
         (__builtin_bit_cast(unsigned, lo) >> 16);
}

#define AS1 __attribute__((address_space(1)))
#define AS3 __attribute__((address_space(3)))
__device__ __forceinline__ void gload_lds16(const void* g, void* l) {
  __builtin_amdgcn_global_load_lds((const AS1 void*)g, (AS3 void*)l, 16, 0, 0);
}

// ---------------- fp32 -> bf16 convert ----------------
__global__ __launch_bounds__(256) void k_cvt(const float* __restrict__ in,
                                             unsigned short* __restrict__ out, int n4) {
  int i = blockIdx.x * 256 + threadIdx.x;
  if (i < n4) {
    float4 v = ((const float4*)in)[i];
    ushort4v o = { f2bf(v.x), f2bf(v.y), f2bf(v.z), f2bf(v.w) };
    ((ushort4v*)out)[i] = o;
  }
}

// ---------------- bias concat: bqkv = [bq|bk|bv] ----------------
__global__ __launch_bounds__(256) void k_bcat(const float* __restrict__ bq,
                                              const float* __restrict__ bk,
                                              const float* __restrict__ bv,
                                              float* __restrict__ o) {
  int i = blockIdx.x * 256 + threadIdx.x;
  o[i] = (i < 1024) ? bq[i] : (i < 2048) ? bk[i - 1024] : bv[i - 2048];
}

// ---------------- W [K][N] fp32 -> Wt [N][K] bf16 ----------------
__global__ __launch_bounds__(256) void k_transpose(const float* __restrict__ W,
                                                   unsigned short* __restrict__ Wt,
                                                   int K, int N) {
  __shared__ float tile[32][33];
  const int n0 = blockIdx.x * 32, k0 = blockIdx.y * 32;
  const int c = threadIdx.x & 31, r4 = threadIdx.x >> 5;
#pragma unroll
  for (int i = 0; i < 4; i++) {
    int r = r4 + i * 8;
    tile[r][c] = W[(size_t)(k0 + r) * N + n0 + c];
  }
  __syncthreads();
#pragma unroll
  for (int i = 0; i < 4; i++) {
    int r = r4 + i * 8;
    Wt[(size_t)(n0 + r) * K + k0 + c] = f2bf(tile[c][r]);
  }
}

// ============ GEMM: 256x256 tile, BK=32, 8 waves (2Mx4N, 128x64/wave) ============
// (structure unchanged from round 5 — phase-interleaved, 3 buffers, counted vmcnt)
template <int MODE, bool SPLIT>
__global__ __launch_bounds__(512, 2) void k_gemm(const unsigned short* __restrict__ A,
                                                 const unsigned short* __restrict__ Bt,
                                                 const float* __restrict__ bias,
                                                 void* __restrict__ out0,
                                                 void* __restrict__ out1,
                                                 void* __restrict__ out2,
                                                 int M, int N, int Kfull) {
  __shared__ unsigned short As[3 * 256 * 32];
  __shared__ unsigned short Bs[3 * 256 * 32];
  const int t = threadIdx.x;
  const int lane = t & 63;
  const int w = t >> 6;
  const int li = lane & 15, lg = lane >> 4;
  const int wm8 = w >> 2, wn4 = w & 3;

  const unsigned nwg = gridDim.x * gridDim.y;
  const unsigned lin = blockIdx.y * gridDim.x + blockIdx.x;
  const unsigned q8 = nwg >> 3, r8 = nwg & 7, xcd = lin & 7, pos = lin >> 3;
  const unsigned swz = (xcd < r8 ? xcd * (q8 + 1) : r8 * (q8 + 1) + (xcd - r8) * q8) + pos;
  int bx = swz % gridDim.x, by = swz / gridDim.x;

  int kp = 0, Ksub = Kfull;
  if (SPLIT) {
    const int hx = gridDim.x >> 1;
    kp = bx >= hx;
    bx -= kp * hx;
    Ksub = Kfull >> 1;
  }
  const int bm = by * 256, bn = bx * 256;
  const size_t koff = (size_t)kp * Ksub;
  const int NT = Ksub / 32;

  const int sr0 = w * 16 + (lane >> 2);
  const int sr1 = sr0 + 128;
  const int sl = lane & 3;
  const unsigned short* pA0 = A + (size_t)(bm + sr0) * Kfull + koff + ((sl ^ ((sr0 >> 1) & 3)) << 3);
  const unsigned short* pA1 = A + (size_t)(bm + sr1) * Kfull + koff + ((sl ^ ((sr1 >> 1) & 3)) << 3);
  const unsigned short* pB0 = Bt + (size_t)(bn + sr0) * Kfull + koff + ((sl ^ ((sr0 >> 1) & 3)) << 3);
  const unsigned short* pB1 = Bt + (size_t)(bn + sr1) * Kfull + koff + ((sl ^ ((sr1 >> 1) & 3)) << 3);

  f32x4 acc[8][4] = {};

  auto stageA = [&](int buf, int tt) {
    gload_lds16(pA0 + tt * 32, &As[buf * 8192 + w * 512]);
    gload_lds16(pA1 + tt * 32, &As[buf * 8192 + 4096 + w * 512]);
  };
  auto stageB = [&](int buf, int tt) {
    gload_lds16(pB0 + tt * 32, &Bs[buf * 8192 + w * 512]);
    gload_lds16(pB1 + tt * 32, &Bs[buf * 8192 + 4096 + w * 512]);
  };

  stageA(0, 0); stageB(0, 0);
  stageA(1, 1); stageB(1, 1);
  asm volatile("s_waitcnt vmcnt(4)" ::: "memory");
  __builtin_amdgcn_s_barrier();

  int buf = 0;
  for (int tt = 0; tt < NT; ++tt) {
    const int nb = (buf + 2 >= 3) ? buf - 1 : buf + 2;
    const unsigned short* Ab = &As[buf * 8192];
    const unsigned short* Bb = &Bs[buf * 8192];
    bf16x8 av[4], bv_[4];
#pragma unroll
    for (int m = 0; m < 4; m++) {
      const int r = wm8 * 128 + m * 16 + li;
      av[m] = *(const bf16x8*)&Ab[r * 32 + ((lg ^ ((r >> 1) & 3)) << 3)];
    }
#pragma unroll
    for (int n = 0; n < 4; n++) {
      const int r = wn4 * 64 + n * 16 + li;
      bv_[n] = *(const bf16x8*)&Bb[r * 32 + ((lg ^ ((r >> 1) & 3)) << 3)];
    }
    if (tt + 2 < NT) stageA(nb, tt + 2);
    __builtin_amdgcn_s_barrier();
    __builtin_amdgcn_s_setprio(1);
#pragma unroll
    for (int m = 0; m < 4; m++)
#pragma unroll
      for (int n = 0; n < 4; n++)
        acc[m][n] = __builtin_amdgcn_mfma_f32_16x16x32_bf16(av[m], bv_[n], acc[m][n], 0, 0, 0);
    __builtin_amdgcn_s_setprio(0);
    bf16x8 av2[4];
#pragma unroll
    for (int m = 0; m < 4; m++) {
      const int r = wm8 * 128 + 64 + m * 16 + li;
      av2[m] = *(const bf16x8*)&Ab[r * 32 + ((lg ^ ((r >> 1) & 3)) << 3)];
    }
    if (tt + 2 < NT) stageB(nb, tt + 2);
    __builtin_amdgcn_s_barrier();
    __builtin_amdgcn_s_setprio(1);
#pragma unroll
    for (int m = 0; m < 4; m++)
#pragma unroll
      for (int n = 0; n < 4; n++)
        acc[m + 4][n] = __builtin_amdgcn_mfma_f32_16x16x32_bf16(av2[m], bv_[n], acc[m + 4][n], 0, 0, 0);
    __builtin_amdgcn_s_setprio(0);
    if (tt + 2 < NT) asm volatile("s_waitcnt vmcnt(4)" ::: "memory");
    else             asm volatile("s_waitcnt vmcnt(0)" ::: "memory");
    __builtin_amdgcn_s_barrier();
    buf = (buf == 2) ? 0 : buf + 1;
  }

#pragma unroll
  for (int m = 0; m < 8; m++) {
    const int row0 = bm + wm8 * 128 + m * 16 + lg * 4;
#pragma unroll
    for (int n = 0; n < 4; n++) {
      const int gcol = bn + wn4 * 64 + n * 16 + li;
      if (MODE == 0) {
        float* dst = (float*)(kp ? out1 : out0);
        const float bvc = (!SPLIT || kp == 0) ? bias[gcol] : 0.f;
#pragma unroll
        for (int j = 0; j < 4; j++)
          dst[(size_t)(row0 + j) * N + gcol] = acc[m][n][j] + bvc;
      } else if (MODE == 2) {
        const float bvc = bias[gcol];
#pragma unroll
        for (int j = 0; j < 4; j++)
          ((unsigned short*)out0)[(size_t)(row0 + j) * N + gcol] = f2bf(fmaxf(acc[m][n][j] + bvc, 0.f));
      } else {  // MODE 3: fused QKV; Q gets the softmax scale folded in
        const float bvc = bias[gcol];
        const int region = gcol >> 10, lcol = gcol & 1023;
        if (region < 2) {
          unsigned short* dst = (unsigned short*)(region ? out1 : out0);
          const float sc = region ? 1.f : QSCALE;
#pragma unroll
          for (int j = 0; j < 4; j++)
            dst[(size_t)(row0 + j) * MODEL + lcol] = f2bf((acc[m][n][j] + bvc) * sc);
        } else {
          ushort4v o = {f2bf(acc[m][n][0] + bvc), f2bf(acc[m][n][1] + bvc),
                        f2bf(acc[m][n][2] + bvc), f2bf(acc[m][n][3] + bvc)};
          *(ushort4v*)&((unsigned short*)out2)[(size_t)lcol * MROWS + row0] = o;
        }
      }
    }
  }
}

// ---------------- flash attention (exp2-domain softmax, ones-MFMA l-sum) ----
__global__ __launch_bounds__(256, 3) void k_attn(const unsigned short* __restrict__ q,
                                                 const unsigned short* __restrict__ kptr,
                                                 const unsigned short* __restrict__ vt,
                                                 const int* __restrict__ mask,
                                                 unsigned short* __restrict__ ctx) {
  __shared__ unsigned short Ks[2][64 * 64];
  __shared__ unsigned short Vs[2][64 * 64];
  __shared__ unsigned short Ps[4][32 * 64];
  const int t = threadIdx.x, lane = t & 63, w = t >> 6;
  const int li = lane & 15, lg = lane >> 4;
  const int bh = blockIdx.y, b = bh >> 4, h = bh & 15;
  const int q0 = blockIdx.x * 128;
  const size_t basebs = (size_t)b * SEQ;
  const int sw = 8 * (li & 7);
  const int srow = lane >> 3;
  const int scsw = ((lane & 7) ^ srow) * 8;

  auto stageKV = [&](int buf, int kt) {
#pragma unroll
    for (int i = 0; i < 2; i++) {
      const int row = i * 32 + w * 8 + srow;
      gload_lds16(kptr + (basebs + kt + row) * MODEL + h * 64 + scsw,
                  &Ks[buf][i * 2048 + w * 512]);
    }
#pragma unroll
    for (int i = 0; i < 2; i++) {
      const int row = i * 32 + w * 8 + srow;
      gload_lds16(vt + (size_t)(h * 64 + row) * MROWS + basebs + kt + scsw,
                  &Vs[buf][i * 2048 + w * 512]);
    }
  };

  stageKV(0, 0);

  bf16x8 qf[2][2];
#pragma unroll
  for (int m = 0; m < 2; m++)
#pragma unroll
    for (int kk = 0; kk < 2; kk++) {
      int row = q0 + w * 32 + m * 16 + li;
      qf[m][kk] = *(const bf16x8*)&q[(basebs + row) * MODEL + h * 64 + kk * 32 + lg * 8];
    }

  // ones fragment for the l-sum MFMA (all-1 A operand: layout-independent)
  const unsigned short one_bits = 0x3F80;
  const __bf16 oneb = __builtin_bit_cast(__bf16, one_bits);
  const bf16x8 ones = {oneb, oneb, oneb, oneb, oneb, oneb, oneb, oneb};

  f32x4 acc_oT[4][2] = {};
  f32x4 acc_l[2] = {};
  float mrow[2] = {-3e38f, -3e38f};

  int cur = 0;
  for (int kt = 0; kt < SEQ; kt += 64) {
    int4 mk4[4];
#pragma unroll
    for (int n = 0; n < 4; n++)
      mk4[n] = *(const int4*)&mask[b * SEQ + kt + n * 16 + lg * 4];

    const bool notlast = (kt + 64 < SEQ);
    if (notlast) {
      stageKV(cur ^ 1, kt + 64);
      asm volatile("s_waitcnt vmcnt(8)" ::: "memory");
    } else {
      asm volatile("s_waitcnt vmcnt(4)" ::: "memory");
    }
    __builtin_amdgcn_s_barrier();

    // S^T = K Q^T (already in exp2 domain via Q pre-scale)
    f32x4 sacc[2][4] = {};
    __builtin_amdgcn_s_setprio(1);
#pragma unroll
    for (int n = 0; n < 4; n++) {
      const int rb = (n * 16 + li) * 64;
      bf16x8 kf0 = *(const bf16x8*)&Ks[cur][rb + ((lg * 8) ^ sw)];
      bf16x8 kf1 = *(const bf16x8*)&Ks[cur][rb + ((32 + lg * 8) ^ sw)];
#pragma unroll
      for (int m = 0; m < 2; m++) {
        sacc[m][n] = __builtin_amdgcn_mfma_f32_16x16x32_bf16(kf0, qf[m][0], sacc[m][n], 0, 0, 0);
        sacc[m][n] = __builtin_amdgcn_mfma_f32_16x16x32_bf16(kf1, qf[m][1], sacc[m][n], 0, 0, 0);
      }
    }
    __builtin_amdgcn_s_setprio(0);

    int mand = mk4[0].x & mk4[0].y & mk4[0].z & mk4[0].w;
    mand &= mk4[1].x & mk4[1].y & mk4[1].z & mk4[1].w;
    mand &= mk4[2].x & mk4[2].y & mk4[2].z & mk4[2].w;
    mand &= mk4[3].x & mk4[3].y & mk4[3].z & mk4[3].w;
    const bool fast = __all(mand != 0);

#pragma unroll
    for (int m = 0; m < 2; m++) {
      if (!fast) {
#pragma unroll
        for (int n = 0; n < 4; n++) {
          const int mks[4] = {mk4[n].x, mk4[n].y, mk4[n].z, mk4[n].w};
#pragma unroll
          for (int j = 0; j < 4; j++)
            sacc[m][n][j] = (mks[j] == 0) ? -1e30f : sacc[m][n][j];
        }
      }
      // pairwise max tree (fuses to v_max3)
      float t0 = fmaxf(fmaxf(sacc[m][0][0], sacc[m][0][1]), fmaxf(sacc[m][0][2], sacc[m][0][3]));
      float t1 = fmaxf(fmaxf(sacc[m][1][0], sacc[m][1][1]), fmaxf(sacc[m][1][2], sacc[m][1][3]));
      float t2 = fmaxf(fmaxf(sacc[m][2][0], sacc[m][2][1]), fmaxf(sacc[m][2][2], sacc[m][2][3]));
      float t3 = fmaxf(fmaxf(sacc[m][3][0], sacc[m][3][1]), fmaxf(sacc[m][3][2], sacc[m][3][3]));
      float rmax = fmaxf(fmaxf(t0, t1), fmaxf(t2, t3));
      rmax = fmaxf(rmax, __shfl_xor(rmax, 16));
      rmax = fmaxf(rmax, __shfl_xor(rmax, 32));
      // defer-max: rescale only when running max grew by > 8*log2e
      if (!__all(rmax <= mrow[m] + DEFER_THR)) {
        float mnew = fmaxf(mrow[m], rmax);
        float alpha = __ocml_native_exp2_f32(mrow[m] - mnew);
        mrow[m] = mnew;
        acc_l[m] *= alpha;
#pragma unroll
        for (int nd = 0; nd < 4; nd++)
#pragma unroll
          for (int j = 0; j < 4; j++) acc_oT[nd][m][j] *= alpha;
      }
#pragma unroll
      for (int n = 0; n < 4; n++) {
        float p0 = __ocml_native_exp2_f32(sacc[m][n][0] - mrow[m]);
        float p1 = __ocml_native_exp2_f32(sacc[m][n][1] - mrow[m]);
        float p2 = __ocml_native_exp2_f32(sacc[m][n][2] - mrow[m]);
        float p3 = __ocml_native_exp2_f32(sacc[m][n][3] - mrow[m]);
        uint2 pk = {packbf_trunc(p0, p1), packbf_trunc(p2, p3)};
        *(uint2*)&Ps[w][(m * 16 + li) * 64 + ((n * 16 + lg * 4) ^ sw)] = pk;
      }
    }
    asm volatile("s_waitcnt lgkmcnt(0)" ::: "memory");

    // O^T += Vt * P ; l += ones * P  (same accumulator discipline)
    __builtin_amdgcn_s_setprio(1);
#pragma unroll
    for (int n2 = 0; n2 < 2; n2++) {
      const int kof = (n2 * 32 + lg * 8) ^ sw;
      bf16x8 pa0 = *(const bf16x8*)&Ps[w][li * 64 + kof];
      bf16x8 pa1 = *(const bf16x8*)&Ps[w][(16 + li) * 64 + kof];
#pragma unroll
      for (int nd = 0; nd < 4; nd++) {
        bf16x8 vfr = *(const bf16x8*)&Vs[cur][(nd * 16 + li) * 64 + kof];
        acc_oT[nd][0] = __builtin_amdgcn_mfma_f32_16x16x32_bf16(vfr, pa0, acc_oT[nd][0], 0, 0, 0);
        acc_oT[nd][1] = __builtin_amdgcn_mfma_f32_16x16x32_bf16(vfr, pa1, acc_oT[nd][1], 0, 0, 0);
      }
      acc_l[0] = __builtin_amdgcn_mfma_f32_16x16x32_bf16(ones, pa0, acc_l[0], 0, 0, 0);
      acc_l[1] = __builtin_amdgcn_mfma_f32_16x16x32_bf16(ones, pa1, acc_l[1], 0, 0, 0);
    }
    __builtin_amdgcn_s_setprio(0);
    __builtin_amdgcn_sched_barrier(0);
    __builtin_amdgcn_s_barrier();
    cur ^= 1;
  }

#pragma unroll
  for (int m = 0; m < 2; m++) {
    const float rl = 1.f / acc_l[m][0];
    const size_t rowoff = (basebs + q0 + w * 32 + m * 16 + li) * (size_t)MODEL + h * 64;
#pragma unroll
    for (int nd = 0; nd < 4; nd++) {
      ushort4v o = {f2bf(acc_oT[nd][m][0] * rl), f2bf(acc_oT[nd][m][1] * rl),
                    f2bf(acc_oT[nd][m][2] * rl), f2bf(acc_oT[nd][m][3] * rl)};
      *(ushort4v*)&ctx[rowoff + nd * 16 + lg * 4] = o;
    }
  }
}

// ---------------- residual + residual + LayerNorm (3 input streams) ----------------
template <bool WB>
__global__ __launch_bounds__(256) void k_ln3(const float* __restrict__ a,
                                             const float* __restrict__ b0,
                                             const float* __restrict__ b1,
                                             const float* __restrict__ gamma,
                                             const float* __restrict__ beta,
                                             float* __restrict__ outf,
                                             unsigned short* __restrict__ outb) {
  const int row = blockIdx.x;
  const int t = threadIdx.x;
  const size_t off = (size_t)row * MODEL + t * 4;
  float4 xa = *(const float4*)&a[off];
  float4 x0 = *(const float4*)&b0[off];
  float4 x1 = *(const float4*)&b1[off];
  float z0 = xa.x + x0.x + x1.x, z1 = xa.y + x0.y + x1.y;
  float z2 = xa.z + x0.z + x1.z, z3 = xa.w + x0.w + x1.w;
  float s = z0 + z1 + z2 + z3;
  float ss = z0 * z0 + z1 * z1 + z2 * z2 + z3 * z3;
#pragma unroll
  for (int o = 1; o < 64; o <<= 1) { s += __shfl_xor(s, o); ss += __shfl_xor(ss, o); }
  __shared__ float red[8];
  const int lane = t & 63, w = t >> 6;
  if (lane == 0) { red[w] = s; red[4 + w] = ss; }
  __syncthreads();
  s = red[0] + red[1] + red[2] + red[3];
  ss = red[4] + red[5] + red[6] + red[7];
  float mu = s * (1.f / MODEL);
  float var = ss * (1.f / MODEL) - mu * mu;
  float inv = rsqrtf(var + 1e-5f);
  float4 g = *(const float4*)&gamma[t * 4];
  float4 be = *(const float4*)&beta[t * 4];
  float o0 = (z0 - mu) * inv * g.x + be.x;
  float o1 = (z1 - mu) * inv * g.y + be.y;
  float o2 = (z2 - mu) * inv * g.z + be.z;
  float o3 = (z3 - mu) * inv * g.w + be.w;
  float4 ov = {o0, o1, o2, o3};
  *(float4*)&outf[off] = ov;
  if (WB) {
    ushort4v ob = {f2bf(o0), f2bf(o1), f2bf(o2), f2bf(o3)};
    *(ushort4v*)&outb[off] = ob;
  }
}

extern "C" void kernel_launch(void* const* d_in, const int* in_sizes, int n_in,
                              void* d_out, int out_size, void* d_ws, size_t ws_size,
                              hipStream_t stream) {
  (void)in_sizes; (void)n_in; (void)out_size; (void)ws_size;
  const float* x   = (const float*)d_in[0];
  const int*   mask= (const int*)d_in[1];
  const float* Wq  = (const float*)d_in[2];
  const float* bq  = (const float*)d_in[3];
  const float* Wk  = (const float*)d_in[4];
  const float* bk  = (const float*)d_in[5];
  const float* Wv  = (const float*)d_in[6];
  const float* bv  = (const float*)d_in[7];
  const float* Wo  = (const float*)d_in[8];
  const float* bo  = (const float*)d_in[9];
  const float* g1  = (const float*)d_in[10];
  const float* be1 = (const float*)d_in[11];
  const float* W1  = (const float*)d_in[12];
  const float* b1  = (const float*)d_in[13];
  const float* W2  = (const float*)d_in[14];
  const float* b2  = (const float*)d_in[15];
  const float* g2  = (const float*)d_in[16];
  const float* be2 = (const float*)d_in[17];
  float* out = (float*)d_out;

  char* p = (char*)d_ws;
  auto alloc = [&](size_t bytes) { char* r = p; p += (bytes + 255) & ~(size_t)255; return r; };
  unsigned short* xb    = (unsigned short*)alloc((size_t)MROWS * MODEL * 2);
  unsigned short* y1b   = (unsigned short*)alloc((size_t)MROWS * MODEL * 2);
  unsigned short* WqkvT = (unsigned short*)alloc((size_t)3 * MODEL * MODEL * 2);
  unsigned short* WoT   = (unsigned short*)alloc((size_t)MODEL * MODEL * 2);
  unsigned short* W1T   = (unsigned short*)alloc((size_t)MODEL * INNER * 2);
  unsigned short* W2T   = (unsigned short*)alloc((size_t)INNER * MODEL * 2);
  float* bqkv           = (float*)alloc(3072 * 4);
  unsigned short* qb    = (unsigned short*)alloc((size_t)MROWS * MODEL * 2);
  unsigned short* kb    = (unsigned short*)alloc((size_t)MROWS * MODEL * 2);
  unsigned short* vtb   = (unsigned short*)alloc((size_t)MODEL * MROWS * 2);
  unsigned short* ctxb  = (unsigned short*)alloc((size_t)MROWS * MODEL * 2);
  float* attn_out       = (float*)alloc((size_t)MROWS * MODEL * 4);
  float* y1f            = (float*)alloc((size_t)MROWS * MODEL * 4);
  unsigned short* h1 = qb;
  float* p1wo = (float*)kb;
  float* ff   = attn_out;
  float* p1ff = (float*)xb;

  k_cvt<<<(MROWS * MODEL / 4) / 256, 256, 0, stream>>>(x, xb, MROWS * MODEL / 4);
  k_bcat<<<12, 256, 0, stream>>>(bq, bk, bv, bqkv);
  k_transpose<<<dim3(MODEL / 32, MODEL / 32), 256, 0, stream>>>(Wq, WqkvT, MODEL, MODEL);
  k_transpose<<<dim3(MODEL / 32, MODEL / 32), 256, 0, stream>>>(Wk, WqkvT + (size_t)MODEL * MODEL, MODEL, MODEL);
  k_transpose<<<dim3(MODEL / 32, MODEL / 32), 256, 0, stream>>>(Wv, WqkvT + (size_t)2 * MODEL * MODEL, MODEL, MODEL);
  k_transpose<<<dim3(MODEL / 32, MODEL / 32), 256, 0, stream>>>(Wo, WoT, MODEL, MODEL);
  k_transpose<<<dim3(INNER / 32, MODEL / 32), 256, 0, stream>>>(W1, W1T, MODEL, INNER);
  k_transpose<<<dim3(MODEL / 32, INNER / 32), 256, 0, stream>>>(W2, W2T, INNER, MODEL);

  k_gemm<3, false><<<dim3(12, MROWS / 256), 512, 0, stream>>>(xb, WqkvT, bqkv, qb, kb, vtb, MROWS, 3072, MODEL);

  k_attn<<<dim3(SEQ / 128, BATCH * NHEADS), 256, 0, stream>>>(qb, kb, vtb, mask, ctxb);

  k_gemm<0, true><<<dim3(8, MROWS / 256), 512, 0, stream>>>(ctxb, WoT, bo, attn_out, p1wo, nullptr, MROWS, MODEL, MODEL);

  k_ln3<true><<<MROWS, 256, 0, stream>>>(x, attn_out, p1wo, g1, be1, y1f, y1b);

  k_gemm<2, false><<<dim3(INNER / 256, MROWS / 256), 512, 0, stream>>>(y1b, W1T, b1, h1, nullptr, nullptr, MROWS, INNER, MODEL);

  k_gemm<0, true><<<dim3(8, MROWS / 256), 512, 0, stream>>>(h1, W2T, b2, ff, p1ff, nullptr, MROWS, MODEL, INNER);

  k_ln3<false><<<MROWS, 256, 0, stream>>>(y1f, ff, p1ff, g2, be2, out, nullptr);
}

// Round 8
// 421.297 us; speedup vs baseline: 1.6963x; 1.0852x over previous
//
#include <hip/hip_runtime.h>
#include <stdint.h>

#define MODEL 1024
#define INNER 4096
#define NHEADS 16
#define HDIM 64
#define BATCH 4
#define SEQ 2048
#define MROWS (BATCH*SEQ)

// Q pre-scaled by 1/sqrt(HDIM)*log2(e) at QKV epilogue -> QK^T in exp2 domain.
#define QSCALE 0.18033688011112042f
#define DEFER_THR 11.541560327111708f

typedef __bf16 bf16x8 __attribute__((ext_vector_type(8)));
typedef float f32x4 __attribute__((ext_vector_type(4)));
typedef float f32x16 __attribute__((ext_vector_type(16)));
typedef unsigned short ushort4v __attribute__((ext_vector_type(4)));
typedef unsigned uint4v __attribute__((ext_vector_type(4)));

extern "C" __device__ float __ocml_native_exp2_f32(float);

__device__ __forceinline__ unsigned short f2bf(float f) {
  unsigned u = __builtin_bit_cast(unsigned, f);
  u += 0x7FFFu + ((u >> 16) & 1u);
  return (unsigned short)(u >> 16);
}
__device__ __forceinline__ float bf2f(unsigned short u) {
  return __builtin_bit_cast(float, (unsigned)u << 16);
}
__device__ __forceinline__ unsigned packbf_trunc(float lo, float hi) {
  return (__builtin_bit_cast(unsigned, hi) & 0xFFFF0000u) |
         (__builtin_bit_cast(unsigned, lo) >> 16);
}

#define AS1 __attribute__((address_space(1)))
#define AS3 __attribute__((address_space(3)))
__device__ __forceinline__ void gload_lds16(const void* g, void* l) {
  __builtin_amdgcn_global_load_lds((const AS1 void*)g, (AS3 void*)l, 16, 0, 0);
}

// ---------------- fp32 -> bf16 convert ----------------
__global__ __launch_bounds__(256) void k_cvt(const float* __restrict__ in,
                                             unsigned short* __restrict__ out, int n4) {
  int i = blockIdx.x * 256 + threadIdx.x;
  if (i < n4) {
    float4 v = ((const float4*)in)[i];
    ushort4v o = { f2bf(v.x), f2bf(v.y), f2bf(v.z), f2bf(v.w) };
    ((ushort4v*)out)[i] = o;
  }
}

// ---------------- bias concat: bqkv = [bq|bk|bv] ----------------
__global__ __launch_bounds__(256) void k_bcat(const float* __restrict__ bq,
                                              const float* __restrict__ bk,
                                              const float* __restrict__ bv,
                                              float* __restrict__ o) {
  int i = blockIdx.x * 256 + threadIdx.x;
  o[i] = (i < 1024) ? bq[i] : (i < 2048) ? bk[i - 1024] : bv[i - 2048];
}

// ---------------- W [K][N] fp32 -> Wt [N][K] bf16 ----------------
__global__ __launch_bounds__(256) void k_transpose(const float* __restrict__ W,
                                                   unsigned short* __restrict__ Wt,
                                                   int K, int N) {
  __shared__ float tile[32][33];
  const int n0 = blockIdx.x * 32, k0 = blockIdx.y * 32;
  const int c = threadIdx.x & 31, r4 = threadIdx.x >> 5;
#pragma unroll
  for (int i = 0; i < 4; i++) {
    int r = r4 + i * 8;
    tile[r][c] = W[(size_t)(k0 + r) * N + n0 + c];
  }
  __syncthreads();
#pragma unroll
  for (int i = 0; i < 4; i++) {
    int r = r4 + i * 8;
    Wt[(size_t)(n0 + r) * K + k0 + c] = f2bf(tile[c][r]);
  }
}

// ============ GEMM: 256x256 tile, BK=32, 8 waves (structure = round 5/6) ============
// MODE: 0 = bf16 partial out (SPLIT: partials to out0/out1, bias on half 0)
//       2 = bf16 + relu ; 3 = fused QKV (out0=q bf16 *QSCALE, out1=k, out2=v^T)
template <int MODE, bool SPLIT>
__global__ __launch_bounds__(512, 2) void k_gemm(const unsigned short* __restrict__ A,
                                                 const unsigned short* __restrict__ Bt,
                                                 const float* __restrict__ bias,
                                                 void* __restrict__ out0,
                                                 void* __restrict__ out1,
                                                 void* __restrict__ out2,
                                                 int M, int N, int Kfull) {
  __shared__ unsigned short As[3 * 256 * 32];
  __shared__ unsigned short Bs[3 * 256 * 32];
  const int t = threadIdx.x;
  const int lane = t & 63;
  const int w = t >> 6;
  const int li = lane & 15, lg = lane >> 4;
  const int wm8 = w >> 2, wn4 = w & 3;

  const unsigned nwg = gridDim.x * gridDim.y;
  const unsigned lin = blockIdx.y * gridDim.x + blockIdx.x;
  const unsigned q8 = nwg >> 3, r8 = nwg & 7, xcd = lin & 7, pos = lin >> 3;
  const unsigned swz = (xcd < r8 ? xcd * (q8 + 1) : r8 * (q8 + 1) + (xcd - r8) * q8) + pos;
  int bx = swz % gridDim.x, by = swz / gridDim.x;

  int kp = 0, Ksub = Kfull;
  if (SPLIT) {
    const int hx = gridDim.x >> 1;
    kp = bx >= hx;
    bx -= kp * hx;
    Ksub = Kfull >> 1;
  }
  const int bm = by * 256, bn = bx * 256;
  const size_t koff = (size_t)kp * Ksub;
  const int NT = Ksub / 32;

  const int sr0 = w * 16 + (lane >> 2);
  const int sr1 = sr0 + 128;
  const int sl = lane & 3;
  const unsigned short* pA0 = A + (size_t)(bm + sr0) * Kfull + koff + ((sl ^ ((sr0 >> 1) & 3)) << 3);
  const unsigned short* pA1 = A + (size_t)(bm + sr1) * Kfull + koff + ((sl ^ ((sr1 >> 1) & 3)) << 3);
  const unsigned short* pB0 = Bt + (size_t)(bn + sr0) * Kfull + koff + ((sl ^ ((sr0 >> 1) & 3)) << 3);
  const unsigned short* pB1 = Bt + (size_t)(bn + sr1) * Kfull + koff + ((sl ^ ((sr1 >> 1) & 3)) << 3);

  f32x4 acc[8][4] = {};

  auto stageA = [&](int buf, int tt) {
    gload_lds16(pA0 + tt * 32, &As[buf * 8192 + w * 512]);
    gload_lds16(pA1 + tt * 32, &As[buf * 8192 + 4096 + w * 512]);
  };
  auto stageB = [&](int buf, int tt) {
    gload_lds16(pB0 + tt * 32, &Bs[buf * 8192 + w * 512]);
    gload_lds16(pB1 + tt * 32, &Bs[buf * 8192 + 4096 + w * 512]);
  };

  stageA(0, 0); stageB(0, 0);
  stageA(1, 1); stageB(1, 1);
  asm volatile("s_waitcnt vmcnt(4)" ::: "memory");
  __builtin_amdgcn_s_barrier();

  int buf = 0;
  for (int tt = 0; tt < NT; ++tt) {
    const int nb = (buf + 2 >= 3) ? buf - 1 : buf + 2;
    const unsigned short* Ab = &As[buf * 8192];
    const unsigned short* Bb = &Bs[buf * 8192];
    bf16x8 av[4], bv_[4];
#pragma unroll
    for (int m = 0; m < 4; m++) {
      const int r = wm8 * 128 + m * 16 + li;
      av[m] = *(const bf16x8*)&Ab[r * 32 + ((lg ^ ((r >> 1) & 3)) << 3)];
    }
#pragma unroll
    for (int n = 0; n < 4; n++) {
      const int r = wn4 * 64 + n * 16 + li;
      bv_[n] = *(const bf16x8*)&Bb[r * 32 + ((lg ^ ((r >> 1) & 3)) << 3)];
    }
    if (tt + 2 < NT) stageA(nb, tt + 2);
    __builtin_amdgcn_s_barrier();
    __builtin_amdgcn_s_setprio(1);
#pragma unroll
    for (int m = 0; m < 4; m++)
#pragma unroll
      for (int n = 0; n < 4; n++)
        acc[m][n] = __builtin_amdgcn_mfma_f32_16x16x32_bf16(av[m], bv_[n], acc[m][n], 0, 0, 0);
    __builtin_amdgcn_s_setprio(0);
    bf16x8 av2[4];
#pragma unroll
    for (int m = 0; m < 4; m++) {
      const int r = wm8 * 128 + 64 + m * 16 + li;
      av2[m] = *(const bf16x8*)&Ab[r * 32 + ((lg ^ ((r >> 1) & 3)) << 3)];
    }
    if (tt + 2 < NT) stageB(nb, tt + 2);
    __builtin_amdgcn_s_barrier();
    __builtin_amdgcn_s_setprio(1);
#pragma unroll
    for (int m = 0; m < 4; m++)
#pragma unroll
      for (int n = 0; n < 4; n++)
        acc[m + 4][n] = __builtin_amdgcn_mfma_f32_16x16x32_bf16(av2[m], bv_[n], acc[m + 4][n], 0, 0, 0);
    __builtin_amdgcn_s_setprio(0);
    if (tt + 2 < NT) asm volatile("s_waitcnt vmcnt(4)" ::: "memory");
    else             asm volatile("s_waitcnt vmcnt(0)" ::: "memory");
    __builtin_amdgcn_s_barrier();
    buf = (buf == 2) ? 0 : buf + 1;
  }

#pragma unroll
  for (int m = 0; m < 8; m++) {
    const int row0 = bm + wm8 * 128 + m * 16 + lg * 4;
#pragma unroll
    for (int n = 0; n < 4; n++) {
      const int gcol = bn + wn4 * 64 + n * 16 + li;
      if (MODE == 0) {
        unsigned short* dst = (unsigned short*)(kp ? out1 : out0);
        const float bvc = (kp == 0) ? bias[gcol] : 0.f;
#pragma unroll
        for (int j = 0; j < 4; j++)
          dst[(size_t)(row0 + j) * N + gcol] = f2bf(acc[m][n][j] + bvc);
      } else if (MODE == 2) {
        const float bvc = bias[gcol];
#pragma unroll
        for (int j = 0; j < 4; j++)
          ((unsigned short*)out0)[(size_t)(row0 + j) * N + gcol] = f2bf(fmaxf(acc[m][n][j] + bvc, 0.f));
      } else {
        const float bvc = bias[gcol];
        const int region = gcol >> 10, lcol = gcol & 1023;
        if (region < 2) {
          unsigned short* dst = (unsigned short*)(region ? out1 : out0);
          const float sc = region ? 1.f : QSCALE;
#pragma unroll
          for (int j = 0; j < 4; j++)
            dst[(size_t)(row0 + j) * MODEL + lcol] = f2bf((acc[m][n][j] + bvc) * sc);
        } else {
          ushort4v o = {f2bf(acc[m][n][0] + bvc), f2bf(acc[m][n][1] + bvc),
                        f2bf(acc[m][n][2] + bvc), f2bf(acc[m][n][3] + bvc)};
          *(ushort4v*)&((unsigned short*)out2)[(size_t)lcol * MROWS + row0] = o;
        }
      }
    }
  }
}

// ---------------- flash attention: 32x32x16 MFMA, in-register P ----------------
// S^T = mfma32(K,Q): lane (l31 -> q, hi) holds S rows kv=(r&3)+8*(r>>2)+4*hi (+32kb).
// P never touches LDS: pk pairs are exchanged across wave halves via shfl_xor(32)
// and selected per-destination-half (fix of round-7's src-half indexing bug).
// Mask is pre-packed to a 256B LDS bitmask once per block.
__global__ __launch_bounds__(256, 4) void k_attn(const unsigned short* __restrict__ q,
                                                 const unsigned short* __restrict__ kptr,
                                                 const unsigned short* __restrict__ vt,
                                                 const int* __restrict__ mask,
                                                 unsigned short* __restrict__ ctx) {
  __shared__ unsigned short Ks[2][64 * 64];   // [kv][d], 16B-slot swz ^ (kv&7)
  __shared__ unsigned short Vs[2][64 * 64];   // [d][kv], 16B-slot swz ^ (d&7)
  __shared__ unsigned maskw[SEQ / 32];        // 64 words: bit kv of word kv>>5
  const int t = threadIdx.x, lane = t & 63, w = t >> 6;
  const int l31 = lane & 31, hi = lane >> 5;
  const int bh = blockIdx.y, b = bh >> 4, h = bh & 15;
  const int q0 = blockIdx.x * 128;
  const size_t basebs = (size_t)b * SEQ;
  const int srow = lane >> 3;
  const int scsw = ((lane & 7) ^ srow) * 8;   // pre-swizzled global source col

  // ---- mask bitmask preamble (before any gload_lds; syncthreads drains only this)
  {
    const int base = b * SEQ + t * 8;
    int4 m0 = *(const int4*)&mask[base];
    int4 m1 = *(const int4*)&mask[base + 4];
    unsigned byte = (unsigned)(m0.x != 0) | ((unsigned)(m0.y != 0) << 1) |
                    ((unsigned)(m0.z != 0) << 2) | ((unsigned)(m0.w != 0) << 3) |
                    ((unsigned)(m1.x != 0) << 4) | ((unsigned)(m1.y != 0) << 5) |
                    ((unsigned)(m1.z != 0) << 6) | ((unsigned)(m1.w != 0) << 7);
    ((unsigned char*)maskw)[t] = (unsigned char)byte;
  }
  __syncthreads();

  auto stageKV = [&](int buf, int kt) {
#pragma unroll
    for (int i = 0; i < 2; i++) {
      const int row = i * 32 + w * 8 + srow;
      gload_lds16(kptr + (basebs + kt + row) * MODEL + h * 64 + scsw,
                  &Ks[buf][i * 2048 + w * 512]);
    }
#pragma unroll
    for (int i = 0; i < 2; i++) {
      const int row = i * 32 + w * 8 + srow;   // row = d
      gload_lds16(vt + (size_t)(h * 64 + row) * MROWS + basebs + kt + scsw,
                  &Vs[buf][i * 2048 + w * 512]);
    }
  };

  stageKV(0, 0);

  // Q fragments (B-operand, 4 K=16 slices): lane holds Q[q=l31][d=s*16+hi*8+e]
  bf16x8 qf[4];
#pragma unroll
  for (int s = 0; s < 4; s++)
    qf[s] = *(const bf16x8*)&q[(basebs + q0 + w * 32 + l31) * MODEL + h * 64 + s * 16 + hi * 8];

  f32x16 acc_o[2] = {};   // O^T[d = (r&3)+8*(r>>2)+4*hi + db*32][q = l31]
  float mrow = -3e38f, lrow = 0.f;

  int cur = 0;
  for (int kt = 0; kt < SEQ; kt += 64) {
    if (kt + 64 < SEQ) {
      stageKV(cur ^ 1, kt + 64);
      asm volatile("s_waitcnt vmcnt(4)" ::: "memory");
    } else {
      asm volatile("s_waitcnt vmcnt(0)" ::: "memory");
    }
    __builtin_amdgcn_s_barrier();

    // S^T = K Q^T over 2 kv-blocks x 4 d-slices
    f32x16 sacc[2] = {};
    __builtin_amdgcn_s_setprio(1);
#pragma unroll
    for (int kb = 0; kb < 2; kb++) {
#pragma unroll
      for (int s = 0; s < 4; s++) {
        bf16x8 kf = *(const bf16x8*)&Ks[cur][(kb * 32 + l31) * 64 + (((s * 2 + hi) ^ (l31 & 7)) << 3)];
        sacc[kb] = __builtin_amdgcn_mfma_f32_32x32x16_bf16(kf, qf[s], sacc[kb], 0, 0, 0);
      }
    }
    __builtin_amdgcn_s_setprio(0);

    // mask from LDS bitmask
    const unsigned W0 = maskw[(kt >> 5)], W1 = maskw[(kt >> 5) + 1];
    if ((W0 & W1) != 0xFFFFFFFFu) {
#pragma unroll
      for (int kb = 0; kb < 2; kb++) {
        const unsigned Wb = kb ? W1 : W0;
#pragma unroll
        for (int rq = 0; rq < 4; rq++)
#pragma unroll
          for (int e = 0; e < 4; e++) {
            const int r = rq * 4 + e;
            sacc[kb][r] = ((Wb >> (e + 8 * rq + 4 * hi)) & 1u) ? sacc[kb][r] : -1e30f;
          }
      }
    }

    // row max (own 32 kv) + partner half
    float rmax = -3e38f;
#pragma unroll
    for (int kb = 0; kb < 2; kb++) {
      float t0 = fmaxf(fmaxf(sacc[kb][0], sacc[kb][1]), fmaxf(sacc[kb][2], sacc[kb][3]));
      float t1 = fmaxf(fmaxf(sacc[kb][4], sacc[kb][5]), fmaxf(sacc[kb][6], sacc[kb][7]));
      float t2 = fmaxf(fmaxf(sacc[kb][8], sacc[kb][9]), fmaxf(sacc[kb][10], sacc[kb][11]));
      float t3 = fmaxf(fmaxf(sacc[kb][12], sacc[kb][13]), fmaxf(sacc[kb][14], sacc[kb][15]));
      rmax = fmaxf(rmax, fmaxf(fmaxf(t0, t1), fmaxf(t2, t3)));
    }
    rmax = fmaxf(rmax, __shfl_xor(rmax, 32));

    if (!__all(rmax <= mrow + DEFER_THR)) {
      float mnew = fmaxf(mrow, rmax);
      float alpha = __ocml_native_exp2_f32(mrow - mnew);
      mrow = mnew;
      lrow *= alpha;
#pragma unroll
      for (int db = 0; db < 2; db++)
#pragma unroll
        for (int r = 0; r < 16; r++) acc_o[db][r] *= alpha;
    }

    // exp2, scalar l-sum, pack pairs: pk[kb][i] = P pair kv = 2(i&1)+8(i>>1)+4hi (+1)
    unsigned pk[2][8];
    float tsum = 0.f;
#pragma unroll
    for (int kb = 0; kb < 2; kb++)
#pragma unroll
      for (int i = 0; i < 8; i++) {
        float p0 = __ocml_native_exp2_f32(sacc[kb][2 * i] - mrow);
        float p1 = __ocml_native_exp2_f32(sacc[kb][2 * i + 1] - mrow);
        tsum += p0 + p1;
        pk[kb][i] = packbf_trunc(p0, p1);
      }
    lrow += tsum + __shfl_xor(tsum, 32);

    // PV: build B-operand with cross-half exchange, DEST-half-indexed (the fix):
    // pu0 = pk[4s+2hi]|srcHalf0, pu1 = +1|srcHalf0, pu2 = pk[4s+2hi]|srcHalf1, pu3 = +1|srcHalf1
    __builtin_amdgcn_s_setprio(1);
#pragma unroll
    for (int kb = 0; kb < 2; kb++) {
#pragma unroll
      for (int s = 0; s < 2; s++) {
        const unsigned own0 = pk[kb][4 * s + 0], own1 = pk[kb][4 * s + 1];
        const unsigned own2 = pk[kb][4 * s + 2], own3 = pk[kb][4 * s + 3];
        const unsigned par0 = (unsigned)__shfl_xor((int)own0, 32);
        const unsigned par1 = (unsigned)__shfl_xor((int)own1, 32);
        const unsigned par2 = (unsigned)__shfl_xor((int)own2, 32);
        const unsigned par3 = (unsigned)__shfl_xor((int)own3, 32);
        const unsigned pu0 = hi ? par2 : own0;
        const unsigned pu1 = hi ? par3 : own1;
        const unsigned pu2 = hi ? own2 : par0;
        const unsigned pu3 = hi ? own3 : par1;
        uint4v pu = {pu0, pu1, pu2, pu3};
        bf16x8 paf = __builtin_bit_cast(bf16x8, pu);
#pragma unroll
        for (int db = 0; db < 2; db++) {
          bf16x8 vf = *(const bf16x8*)&Vs[cur][(db * 32 + l31) * 64 + (((kb * 4 + s * 2 + hi) ^ (l31 & 7)) << 3)];
          acc_o[db] = __builtin_amdgcn_mfma_f32_32x32x16_bf16(vf, paf, acc_o[db], 0, 0, 0);
        }
      }
    }
    __builtin_amdgcn_s_setprio(0);
    __builtin_amdgcn_sched_barrier(0);
    __builtin_amdgcn_s_barrier();   // all waves done with cur before it's restaged
    cur ^= 1;
  }

  const float rl = 1.f / lrow;
  const size_t rowoff = (basebs + q0 + w * 32 + l31) * (size_t)MODEL + h * 64;
#pragma unroll
  for (int db = 0; db < 2; db++)
#pragma unroll
    for (int rq = 0; rq < 4; rq++) {
      const int r = rq * 4;
      ushort4v o = {f2bf(acc_o[db][r] * rl), f2bf(acc_o[db][r + 1] * rl),
                    f2bf(acc_o[db][r + 2] * rl), f2bf(acc_o[db][r + 3] * rl)};
      *(ushort4v*)&ctx[rowoff + db * 32 + rq * 8 + 4 * hi] = o;
    }
}

// ---------------- residual + 2 bf16 streams + LayerNorm ----------------
// AF32: a-stream fp32 (LN1, writes bf16 out) / bf16 (LN2, writes fp32 out)
template <bool AF32>
__global__ __launch_bounds__(256) void k_ln(const void* __restrict__ a,
                                            const unsigned short* __restrict__ b0,
                                            const unsigned short* __restrict__ b1,
                                            const float* __restrict__ gamma,
                                            const float* __restrict__ beta,
                                            float* __restrict__ outf,
                                            unsigned short* __restrict__ outb) {
  const int row = blockIdx.x;
  const int t = threadIdx.x;
  const size_t off = (size_t)row * MODEL + t * 4;
  float4 xa;
  if (AF32) {
    xa = *(const float4*)((const float*)a + off);
  } else {
    ushort4v av = *(const ushort4v*)((const unsigned short*)a + off);
    xa = {bf2f(av.x), bf2f(av.y), bf2f(av.z), bf2f(av.w)};
  }
  ushort4v u0 = *(const ushort4v*)&b0[off];
  ushort4v u1 = *(const ushort4v*)&b1[off];
  float z0 = xa.x + bf2f(u0.x) + bf2f(u1.x);
  float z1 = xa.y + bf2f(u0.y) + bf2f(u1.y);
  float z2 = xa.z + bf2f(u0.z) + bf2f(u1.z);
  float z3 = xa.w + bf2f(u0.w) + bf2f(u1.w);
  float s = z0 + z1 + z2 + z3;
  float ss = z0 * z0 + z1 * z1 + z2 * z2 + z3 * z3;
#pragma unroll
  for (int o = 1; o < 64; o <<= 1) { s += __shfl_xor(s, o); ss += __shfl_xor(ss, o); }
  __shared__ float red[8];
  const int lane = t & 63, w = t >> 6;
  if (lane == 0) { red[w] = s; red[4 + w] = ss; }
  __syncthreads();
  s = red[0] + red[1] + red[2] + red[3];
  ss = red[4] + red[5] + red[6] + red[7];
  float mu = s * (1.f / MODEL);
  float var = ss * (1.f / MODEL) - mu * mu;
  float inv = rsqrtf(var + 1e-5f);
  float4 g = *(const float4*)&gamma[t * 4];
  float4 be = *(const float4*)&beta[t * 4];
  float o0 = (z0 - mu) * inv * g.x + be.x;
  float o1 = (z1 - mu) * inv * g.y + be.y;
  float o2 = (z2 - mu) * inv * g.z + be.z;
  float o3 = (z3 - mu) * inv * g.w + be.w;
  if (AF32) {
    ushort4v ob = {f2bf(o0), f2bf(o1), f2bf(o2), f2bf(o3)};
    *(ushort4v*)&outb[off] = ob;
  } else {
    float4 ov = {o0, o1, o2, o3};
    *(float4*)&outf[off] = ov;
  }
}

extern "C" void kernel_launch(void* const* d_in, const int* in_sizes, int n_in,
                              void* d_out, int out_size, void* d_ws, size_t ws_size,
                              hipStream_t stream) {
  (void)in_sizes; (void)n_in; (void)out_size; (void)ws_size;
  const float* x   = (const float*)d_in[0];
  const int*   mask= (const int*)d_in[1];
  const float* Wq  = (const float*)d_in[2];
  const float* bq  = (const float*)d_in[3];
  const float* Wk  = (const float*)d_in[4];
  const float* bk  = (const float*)d_in[5];
  const float* Wv  = (const float*)d_in[6];
  const float* bv  = (const float*)d_in[7];
  const float* Wo  = (const float*)d_in[8];
  const float* bo  = (const float*)d_in[9];
  const float* g1  = (const float*)d_in[10];
  const float* be1 = (const float*)d_in[11];
  const float* W1  = (const float*)d_in[12];
  const float* b1  = (const float*)d_in[13];
  const float* W2  = (const float*)d_in[14];
  const float* b2  = (const float*)d_in[15];
  const float* g2  = (const float*)d_in[16];
  const float* be2 = (const float*)d_in[17];
  float* out = (float*)d_out;

  char* p = (char*)d_ws;
  auto alloc = [&](size_t bytes) { char* r = p; p += (bytes + 255) & ~(size_t)255; return r; };
  unsigned short* xb    = (unsigned short*)alloc((size_t)MROWS * MODEL * 2);
  unsigned short* y1b   = (unsigned short*)alloc((size_t)MROWS * MODEL * 2);
  unsigned short* WqkvT = (unsigned short*)alloc((size_t)3 * MODEL * MODEL * 2);
  unsigned short* WoT   = (unsigned short*)alloc((size_t)MODEL * MODEL * 2);
  unsigned short* W1T   = (unsigned short*)alloc((size_t)MODEL * INNER * 2);
  unsigned short* W2T   = (unsigned short*)alloc((size_t)INNER * MODEL * 2);
  float* bqkv           = (float*)alloc(3072 * 4);
  unsigned short* qb    = (unsigned short*)alloc((size_t)MROWS * MODEL * 2);
  unsigned short* kb    = (unsigned short*)alloc((size_t)MROWS * MODEL * 2);
  unsigned short* vtb   = (unsigned short*)alloc((size_t)MODEL * MROWS * 2);
  unsigned short* ctxb  = (unsigned short*)alloc((size_t)MROWS * MODEL * 2);
  unsigned short* ao0   = (unsigned short*)alloc((size_t)MROWS * MODEL * 2);
  unsigned short* ao1   = (unsigned short*)alloc((size_t)MROWS * MODEL * 2);
  unsigned short* h1  = qb;    // FF1 out [MROWS][INNER] bf16 over dead qb..ctxb
  unsigned short* ff0 = ao0;   // FF2 partial 0 (ao* dead after LN1)
  unsigned short* ff1 = ao1;   // FF2 partial 1

  k_cvt<<<(MROWS * MODEL / 4) / 256, 256, 0, stream>>>(x, xb, MROWS * MODEL / 4);
  k_bcat<<<12, 256, 0, stream>>>(bq, bk, bv, bqkv);
  k_transpose<<<dim3(MODEL / 32, MODEL / 32), 256, 0, stream>>>(Wq, WqkvT, MODEL, MODEL);
  k_transpose<<<dim3(MODEL / 32, MODEL / 32), 256, 0, stream>>>(Wk, WqkvT + (size_t)MODEL * MODEL, MODEL, MODEL);
  k_transpose<<<dim3(MODEL / 32, MODEL / 32), 256, 0, stream>>>(Wv, WqkvT + (size_t)2 * MODEL * MODEL, MODEL, MODEL);
  k_transpose<<<dim3(MODEL / 32, MODEL / 32), 256, 0, stream>>>(Wo, WoT, MODEL, MODEL);
  k_transpose<<<dim3(INNER / 32, MODEL / 32), 256, 0, stream>>>(W1, W1T, MODEL, INNER);
  k_transpose<<<dim3(MODEL / 32, INNER / 32), 256, 0, stream>>>(W2, W2T, INNER, MODEL);

  // fused QKV: Q (pre-scaled), K row-major; V transposed
  k_gemm<3, false><<<dim3(12, MROWS / 256), 512, 0, stream>>>(xb, WqkvT, bqkv, qb, kb, vtb, MROWS, 3072, MODEL);

  k_attn<<<dim3(SEQ / 128, BATCH * NHEADS), 256, 0, stream>>>(qb, kb, vtb, mask, ctxb);

  // Wo projection, split-K x2, bf16 partials
  k_gemm<0, true><<<dim3(8, MROWS / 256), 512, 0, stream>>>(ctxb, WoT, bo, ao0, ao1, nullptr, MROWS, MODEL, MODEL);

  // LN1: y1b = LN(x + ao0 + ao1)  (bf16 out)
  k_ln<true><<<MROWS, 256, 0, stream>>>(x, ao0, ao1, g1, be1, nullptr, y1b);

  // FF1: h1 = relu(y1 @ W1 + b1)
  k_gemm<2, false><<<dim3(INNER / 256, MROWS / 256), 512, 0, stream>>>(y1b, W1T, b1, h1, nullptr, nullptr, MROWS, INNER, MODEL);

  // FF2 split-K x2, bf16 partials
  k_gemm<0, true><<<dim3(8, MROWS / 256), 512, 0, stream>>>(h1, W2T, b2, ff0, ff1, nullptr, MROWS, MODEL, INNER);

  // LN2 -> out (fp32)
  k_ln<false><<<MROWS, 256, 0, stream>>>(y1b, ff0, ff1, g2, be2, out, nullptr);
}